// Round 1
// baseline (1028.749 us; speedup 1.0000x reference)
//
#include <hip/hip_runtime.h>
#include <hip/hip_bf16.h>
#include <cstring>

typedef __hip_bfloat16 bf16;
typedef __attribute__((ext_vector_type(8))) short short8v;
typedef __attribute__((ext_vector_type(4))) float float4v;

#define V_    32000
#define E_    512
#define H_    512
#define T_    128
#define B_    4
#define D_    4
#define L_    2
#define C0_   2000
#define C1_   10000
#define NT_   125
#define NROW_ 2000          // B*NT*D
#define NH_   2002
#define NTOTC 2162          // 2002 + 128 + 32
#define NSLOT 252           // 17 head + 63 t0 + 172 t1 LSE partial slots per row

__device__ __forceinline__ float bf2f(bf16 v) { return __bfloat162float(v); }
__device__ __forceinline__ unsigned short f2bfu(float f) {
    bf16 h = __float2bfloat16(f);
    union { bf16 h; unsigned short u; } cv; cv.h = h; return cv.u;
}
// dtype-flag helpers: bf==1 -> bf16 input data, bf==0 -> float32
__device__ __forceinline__ float ld1(const void* p, size_t i, int bf) {
    return bf ? bf2f(((const bf16*)p)[i]) : ((const float*)p)[i];
}
__device__ __forceinline__ void st1(void* p, size_t i, int bf, float v) {
    if (bf) ((unsigned short*)p)[i] = f2bfu(v);
    else    ((float*)p)[i] = v;
}

__device__ __forceinline__ void lse_push(float z, float& m, float& s) {
    if (z <= m) { s += __expf(z - m); }
    else        { s = s * __expf(m - z) + 1.0f; m = z; }
}
__device__ __forceinline__ void lse_merge(float m2, float s2, float& m, float& s) {
    float mm = fmaxf(m, m2);
    s = s * __expf(m - mm) + s2 * __expf(m2 - mm);
    m = mm;
}

// ---------------- stage 0: dtype detect (G row 0 is a softmax row) --------
__global__ void k_detect(const void* __restrict__ G, int* __restrict__ flag) {
    int t = threadIdx.x;   // 64 threads
    float s32 = 0.0f;
    for (int k = t; k < 128; k += 64) s32 += ((const float*)G)[k];
    for (int off = 32; off; off >>= 1) s32 += __shfl_down(s32, off);
    if (t == 0) {
        float e32 = fabsf(s32 - 1.0f);
        *flag = (e32 < 0.05f) ? 0 : 1;   // NaN compares false -> bf16 fallback
    }
}

// ---------------- weight conversion + embedding gather (merged) -----------
struct ConvArgs {
    const void* src[9];
    unsigned int off[10];
};
__global__ void k_wembed(ConvArgs a, unsigned short* __restrict__ wb,
                         const int* __restrict__ flagp,
                         const int* __restrict__ x, const void* __restrict__ emb,
                         float* __restrict__ embedded, float* __restrict__ f0,
                         unsigned short* __restrict__ f0b) {
    const int bf = *flagp;
    if (blockIdx.x < 1024) {
        // embedding gather: 262144 elements
        int i = blockIdx.x * 256 + threadIdx.x;
        int bt = i >> 9, e = i & 511;
        int tok = x[bt];
        float v = ld1(emb, (size_t)tok * E_ + e, bf);
        embedded[i] = v; f0[i] = v; f0b[i] = f2bfu(v);
    } else {
        // weight conversion -> contiguous bf16 region (grid-stride)
        unsigned int total = a.off[9];
        unsigned int stride = (gridDim.x - 1024) * 256;
        for (unsigned int i = (blockIdx.x - 1024) * 256 + threadIdx.x; i < total;
             i += stride) {
            int seg = 0;
            while (i >= a.off[seg + 1]) seg++;
            wb[i] = f2bfu(ld1(a.src[seg], i - a.off[seg], bf));
        }
    }
}

// ---------------- wgt[b,i,e] = sum_j G[b,l,j,i] f[b,j,e] ------------------
__global__ void k_wgt(const void* __restrict__ G, const float* __restrict__ f,
                      unsigned short* __restrict__ wgtb, int l,
                      const int* __restrict__ flagp) {
    const int bf = *flagp;
    int i = blockIdx.x * 256 + threadIdx.x;          // 262144
    int e = i & 511;
    int bi = i >> 9;
    int b = bi >> 7, ip = bi & 127;
    size_t gbase = ((size_t)(b * L_ + l) * T_ * T_) + ip;
    const float* fb = f + (size_t)b * T_ * E_ + e;
    float acc = 0.0f;
    #pragma unroll 4
    for (int j = 0; j < T_; ++j)
        acc = fmaf(ld1(G, gbase + (size_t)j * T_, bf), fb[(size_t)j * E_], acc);
    wgtb[i] = f2bfu(acc);
}

// ---------------- MFMA bf16 GEMM core: Z[M,N] = A[M,K] * W[N,K]^T ---------
// MODE 0: gates   (store Z+bias into Zg; blockIdx.z = A/W pair OR K-slice)
// MODE 1: head passA (LSE cols<2002 -> lsep; stats 2000/2001; proj -> p0b/p1b)
// MODE 2: tail passA (LSE over all N -> lsep at slotBase)
// MODE 3: passB (store valid ? z - corr[crIdx] : 0 into out at outColOff)
struct GemmP {
    const unsigned short* A0;
    const unsigned short* A1;
    const unsigned short* W;
    unsigned long long w1off;
    int M, N, K, Nlse;
    float* Zg; int ldz; int zcol1;
    const void* bias0; const void* bias1; int boff;
    void* out; int outColOff;
    float* stats;
    unsigned short* p0b;
    unsigned short* p1b;
    float* lsep; int slotBase;
    const float* corr;
    const int* lengths;
    const int* flagp;
    int gx;       // grid-x width of this segment (for merged dispatch)
    int nrep;     // n-tiles handled per block (amortize per-block overhead)
    int crIdx;    // correction index for MODE 3
    int ksplit;   // split-K factor via blockIdx.z (MODE 0 only)
};

template<int MODE>
__device__ __forceinline__ void gemm_core(const GemmP& p, int bx, int by,
        unsigned short* As, unsigned short* Bs,
        float (*pm)[2], float (*ps)[2]) {
    const int bf = *p.flagp;
    int zsel = 0, kslice = 0;
    if (MODE == 0) {
        if (p.ksplit > 1) kslice = blockIdx.z;
        else              zsel   = blockIdx.z;
    }
    const unsigned short* A  = zsel ? p.A1 : p.A0;
    const unsigned short* Bw = p.W + (zsel ? p.w1off : 0ull);
    const int M = p.M, N = p.N, K = p.K;
    const int m0 = by * 128;
    const int t = threadIdx.x;
    const int wave = t >> 6, lane = t & 63;
    const int wm = wave >> 1, wn = wave & 1;
    const int quad = lane >> 4, l16 = lane & 15;
    const int kcnt = K / p.ksplit;
    const int kbeg = kslice * kcnt;

    for (int nr = 0; nr < p.nrep; ++nr) {
        const int ntile = bx * p.nrep + nr;
        const int n0 = ntile * 128;

        float4v acc[4][4];
        #pragma unroll
        for (int mi = 0; mi < 4; ++mi)
            #pragma unroll
            for (int ni = 0; ni < 4; ++ni)
                acc[mi][ni] = (float4v){0.f, 0.f, 0.f, 0.f};

        for (int kk = 0; kk < kcnt; kk += 32) {
            const int k0 = kbeg + kk;
            if (kk | nr) __syncthreads();
            #pragma unroll
            for (int i = 0; i < 2; ++i) {
                int idx = t + i * 256;
                int row = idx >> 2, seg = idx & 3;
                uint4 av = {0u, 0u, 0u, 0u};
                int gm = m0 + row;
                if (gm < M) av = *(const uint4*)(A + (size_t)gm * K + k0 + seg * 8);
                *(uint4*)(&As[row * 40 + seg * 8]) = av;
                uint4 bv = {0u, 0u, 0u, 0u};
                int gn = n0 + row;
                if (gn < N) bv = *(const uint4*)(Bw + (size_t)gn * K + k0 + seg * 8);
                *(uint4*)(&Bs[row * 40 + seg * 8]) = bv;
            }
            __syncthreads();
            short8v af[4], bfv[4];
            #pragma unroll
            for (int mi = 0; mi < 4; ++mi)
                af[mi] = *(const short8v*)(As + (wm * 64 + mi * 16 + l16) * 40 + quad * 8);
            #pragma unroll
            for (int ni = 0; ni < 4; ++ni)
                bfv[ni] = *(const short8v*)(Bs + (wn * 64 + ni * 16 + l16) * 40 + quad * 8);
            #pragma unroll
            for (int mi = 0; mi < 4; ++mi)
                #pragma unroll
                for (int ni = 0; ni < 4; ++ni)
                    acc[mi][ni] = __builtin_amdgcn_mfma_f32_16x16x32_bf16(
                        af[mi], bfv[ni], acc[mi][ni], 0, 0, 0);
        }

        // ---- epilogue ----
        if (MODE == 0) {
            const void* bias = zsel ? p.bias1 : p.bias0;
            const int zcol = zsel ? p.zcol1 : 0;
            float* Z = p.Zg + (size_t)kslice * p.M * p.ldz;
            #pragma unroll
            for (int mi = 0; mi < 4; ++mi)
                #pragma unroll
                for (int r = 0; r < 4; ++r) {
                    int grow = m0 + wm * 64 + mi * 16 + quad * 4 + r;
                    if (grow >= M) continue;
                    #pragma unroll
                    for (int ni = 0; ni < 4; ++ni) {
                        int gcol = n0 + wn * 64 + ni * 16 + l16;
                        if (gcol < N) {
                            float bv = (kslice == 0) ? ld1(bias, p.boff + gcol, bf) : 0.0f;
                            Z[(size_t)grow * p.ldz + zcol + gcol] = acc[mi][ni][r] + bv;
                        }
                    }
                }
        } else if (MODE == 1) {
            #pragma unroll
            for (int mi = 0; mi < 4; ++mi)
                #pragma unroll
                for (int r = 0; r < 4; ++r) {
                    int grow = m0 + wm * 64 + mi * 16 + quad * 4 + r;
                    if (grow >= M) continue;
                    #pragma unroll
                    for (int ni = 0; ni < 4; ++ni) {
                        int gcol = n0 + wn * 64 + ni * 16 + l16;
                        float v = acc[mi][ni][r];
                        if (gcol >= C0_ && gcol < NH_) p.stats[grow * 8 + 2 + (gcol - C0_)] = v;
                        else if (gcol >= NH_ && gcol < 2130) p.p0b[grow * 128 + (gcol - NH_)] = f2bfu(v);
                        else if (gcol >= 2130 && gcol < NTOTC) p.p1b[grow * 32 + (gcol - 2130)] = f2bfu(v);
                    }
                }
        } else if (MODE == 3) {
            const int crIdx = p.crIdx;
            #pragma unroll
            for (int mi = 0; mi < 4; ++mi)
                #pragma unroll
                for (int r = 0; r < 4; ++r) {
                    int grow = m0 + wm * 64 + mi * 16 + quad * 4 + r;
                    if (grow >= M) continue;
                    int b = grow / 500;
                    int tt = (grow - b * 500) >> 2;
                    bool valid = tt < p.lengths[b];
                    float cr = p.corr[grow * 4 + crIdx];
                    #pragma unroll
                    for (int ni = 0; ni < 4; ++ni) {
                        int gcol = n0 + wn * 64 + ni * 16 + l16;
                        if (gcol < N) {
                            float v = valid ? (acc[mi][ni][r] - cr) : 0.0f;
                            st1(p.out, (size_t)grow * V_ + p.outColOff + gcol, bf, v);
                        }
                    }
                }
        }

        // ---- fused per-tile LSE partials (pass A modes only) ----
        if (MODE == 1 || MODE == 2) {
            const int Nlse = p.Nlse;
            #pragma unroll
            for (int mi = 0; mi < 4; ++mi) {
                #pragma unroll
                for (int r = 0; r < 4; ++r) {
                    float m = -1e30f, s = 0.0f;
                    #pragma unroll
                    for (int ni = 0; ni < 4; ++ni) {
                        int gcol = n0 + wn * 64 + ni * 16 + l16;
                        if (gcol < Nlse) lse_push(acc[mi][ni][r], m, s);
                    }
                    #pragma unroll
                    for (int off = 1; off < 16; off <<= 1) {
                        float m2 = __shfl_xor(m, off), s2 = __shfl_xor(s, off);
                        lse_merge(m2, s2, m, s);
                    }
                    if (l16 == 0) {
                        int rl = wm * 64 + mi * 16 + quad * 4 + r;
                        pm[rl][wn] = m; ps[rl][wn] = s;
                    }
                }
            }
            __syncthreads();
            if (t < 128) {
                int grow = m0 + t;
                if (grow < M) {
                    float m = pm[t][0], s = ps[t][0];
                    lse_merge(pm[t][1], ps[t][1], m, s);
                    float* dst = p.lsep + ((size_t)grow * NSLOT + p.slotBase + ntile) * 2;
                    dst[0] = m; dst[1] = s;
                }
            }
        }
    }
}

__global__ void k_gemm0(GemmP p) {
    __shared__ __align__(16) unsigned short As[128 * 40];
    __shared__ __align__(16) unsigned short Bs[128 * 40];
    __shared__ float pm[128][2], ps[128][2];
    gemm_core<0>(p, blockIdx.x, blockIdx.y, As, Bs, pm, ps);
}
__global__ void k_gemm1(GemmP p) {
    __shared__ __align__(16) unsigned short As[128 * 40];
    __shared__ __align__(16) unsigned short Bs[128 * 40];
    __shared__ float pm[128][2], ps[128][2];
    gemm_core<1>(p, blockIdx.x, blockIdx.y, As, Bs, pm, ps);
}
__global__ void k_gemmA2(GemmP pa, GemmP pb) {
    __shared__ __align__(16) unsigned short As[128 * 40];
    __shared__ __align__(16) unsigned short Bs[128 * 40];
    __shared__ float pm[128][2], ps[128][2];
    int bx = blockIdx.x;
    if (bx < pa.gx) gemm_core<2>(pa, bx, blockIdx.y, As, Bs, pm, ps);
    else            gemm_core<2>(pb, bx - pa.gx, blockIdx.y, As, Bs, pm, ps);
}
__global__ void k_gemmB3(GemmP pa, GemmP pb, GemmP pc) {
    __shared__ __align__(16) unsigned short As[128 * 40];
    __shared__ __align__(16) unsigned short Bs[128 * 40];
    __shared__ float pm[128][2], ps[128][2];
    int bx = blockIdx.x;
    if (bx < pa.gx)              gemm_core<3>(pa, bx, blockIdx.y, As, Bs, pm, ps);
    else if (bx < pa.gx + pb.gx) gemm_core<3>(pb, bx - pa.gx, blockIdx.y, As, Bs, pm, ps);
    else                         gemm_core<3>(pc, bx - pa.gx - pb.gx, blockIdx.y, As, Bs, pm, ps);
}

// ---------------- GRU pointwise ----------------
__device__ __forceinline__ float gru2(float i_r, float i_z, float i_n,
                                      float h_r, float h_z, float h_n, float h) {
    float r = 1.0f / (1.0f + __expf(-(i_r + h_r)));
    float z = 1.0f / (1.0f + __expf(-(i_z + h_z)));
    float n = tanhf(i_n + r * h_n);
    return (1.0f - z) * n + z * h;
}

__global__ void k_apply_enc(const float* __restrict__ gates,
                            const float* __restrict__ hprev,
                            float* __restrict__ hnext,
                            unsigned short* __restrict__ hnextb) {
    int i = blockIdx.x * 256 + threadIdx.x;          // 262144
    int row = i >> 9, k = i & 511;
    const float* g = gates + (size_t)row * 3072;
    float v = gru2(g[k], g[512 + k], g[1024 + k],
                   g[1536 + k], g[2048 + k], g[2560 + k], hprev[i]);
    hnext[i] = v; hnextb[i] = f2bfu(v);
}

// merged: window gather (1,024,000) + h0 init (256,000)
__global__ void k_h0win(const float* __restrict__ embedded,
                        const float* __restrict__ ffin,
                        const int* __restrict__ lengths,
                        unsigned short* __restrict__ winb,
                        float* __restrict__ hdec,
                        unsigned short* __restrict__ hdecb) {
    int i = blockIdx.x * 256 + threadIdx.x;          // 1,280,000 total
    if (i < 1024000) {
        int e = i & 511;
        int wr = i >> 9;
        int d = wr / 500, row = wr - d * 500;
        int b = row / NT_, t = row - b * NT_;
        int tok = (d == 0 && t == 0) ? (lengths[b] - 1) : (t + d - 1);
        winb[i] = f2bfu(embedded[((size_t)(b * T_ + tok) << 9) + e]);
    } else {
        int j = i - 1024000;                         // 256,000
        int row = j >> 9, e = j & 511;
        int b = row / NT_, t = row - b * NT_;
        float v = ffin[((size_t)(b * T_ + t) << 9) + e];
        hdec[j] = v; hdecb[j] = f2bfu(v);
    }
}

__global__ void k_apply_dec(const float* __restrict__ gih,
                            const float* __restrict__ ghh,
                            float* __restrict__ hdec,
                            unsigned short* __restrict__ hdecb,
                            unsigned short* __restrict__ hsb,
                            const int* __restrict__ lengths, int d) {
    int i = blockIdx.x * 256 + threadIdx.x;          // 256000
    int row = i >> 9, k = i & 511;
    int b = row / NT_, t = row - b * NT_;
    const float* gi = gih + (size_t)(d * 500 + row) * 1536;
    const float* gh = ghh + (size_t)row * 1536;
    // sum the 4 split-K partial gate buffers (bias included in slice 0 only)
    float h_r = 0.f, h_z = 0.f, h_n = 0.f;
    #pragma unroll
    for (int s = 0; s < 4; ++s) {
        const float* g = gh + (size_t)s * 768000;
        h_r += g[k]; h_z += g[512 + k]; h_n += g[1024 + k];
    }
    float hn = gru2(gi[k], gi[512 + k], gi[1024 + k], h_r, h_z, h_n, hdec[i]);
    hdec[i] = hn; hdecb[i] = f2bfu(hn);
    bool valid = (t + d) < lengths[b];
    hsb[(((size_t)row * D_ + d) << 9) + k] = valid ? f2bfu(hn) : (unsigned short)0;
}

// ---------------- combine LSE partials -> per-row corrections -------------
__global__ void k_corr2(const float* __restrict__ lsep, const float* __restrict__ stats,
                        float* __restrict__ corr) {
    int r = blockIdx.x * 256 + threadIdx.x;
    if (r >= NROW_) return;
    const float* P = lsep + (size_t)r * NSLOT * 2;
    float m = -1e30f, s = 0.0f;
    for (int i = 0; i < 17; ++i)  lse_merge(P[2 * i], P[2 * i + 1], m, s);
    float ch = m + logf(s);
    float lp0 = stats[r * 8 + 2] - ch;
    float lp1 = stats[r * 8 + 3] - ch;
    m = -1e30f; s = 0.0f;
    for (int i = 17; i < 80; ++i) lse_merge(P[2 * i], P[2 * i + 1], m, s);
    float ct0 = m + logf(s);
    m = -1e30f; s = 0.0f;
    for (int i = 80; i < 252; ++i) lse_merge(P[2 * i], P[2 * i + 1], m, s);
    float ct1 = m + logf(s);
    corr[r * 4 + 0] = ch;
    corr[r * 4 + 1] = ct0 - lp0;
    corr[r * 4 + 2] = ct1 - lp1;
}

// ---------------- workspace layout (float offsets, 16B aligned) -----------
#define OFF_EMB    0u          // 262144
#define OFF_FA     262144u     // 262144
#define OFF_FB     524288u     // 262144
#define OFF_FAB    786432u     // 131072 (262144 bf16)
#define OFF_FBB    917504u     // 131072
#define OFF_WGTB   1048576u    // 131072
#define OFF_GATES  1179648u    // 512*3072 = 1572864
#define OFF_GIH    2752512u    // 2000*1536 = 3072000
#define OFF_GHH    5824512u    // 4*500*1536 = 3072000 (split-K x4 partials)
#define OFF_HDEC   8896512u    // 256000
#define OFF_HDECB  9152512u    // 128000
#define OFF_WINB   9280512u    // 512000 (1,024,000 bf16)
#define OFF_HSB    9792512u    // 512000 (1,024,000 bf16)
#define OFF_P0B    10304512u   // 128000 (256000 bf16)
#define OFF_P1B    10432512u   // 32000  (64000 bf16)
#define OFF_STATS  10464512u   // 16000
#define OFF_CORR   10480512u   // 8000
#define OFF_LSEP   10488512u   // 1008000
#define OFF_WB     11496512u   // 3776752 (7553504 bf16)
#define OFF_FLAG   15273264u

// bf16 weight region sub-offsets (shorts)
#define WO_ENCIH   0u
#define WO_ENCHH   1572864u
#define WO_DECIH   3145728u
#define WO_DECHH   3932160u
#define WO_W1      4718592u    // head_w rows, t0_proj, t1_proj (2162x512)
#define WO_T0O     5825536u    // 8000x128
#define WO_T1O     6849536u    // 22000x32
#define WO_END     7553504u

static inline GemmP defp(const int* lengths, const int* flagp) {
    GemmP p;
    memset(&p, 0, sizeof(p));
    p.nrep = 1; p.ksplit = 1;
    p.lengths = lengths; p.flagp = flagp;
    return p;
}

extern "C" void kernel_launch(void* const* d_in, const int* in_sizes, int n_in,
                              void* d_out, int out_size, void* d_ws, size_t ws_size,
                              hipStream_t stream) {
    (void)in_sizes; (void)n_in; (void)out_size; (void)ws_size;
    const int*  x        = (const int*)d_in[0];
    const int*  lengths  = (const int*)d_in[1];
    const void* G        = d_in[2];
    const void* emb      = d_in[3];
    const void* enc_w_ih = d_in[4];
    const void* enc_w_hh = d_in[5];
    const void* enc_b_ih = d_in[6];
    const void* enc_b_hh = d_in[7];
    const void* dec_w_ih = d_in[8];
    const void* dec_w_hh = d_in[9];
    const void* dec_b_ih = d_in[10];
    const void* dec_b_hh = d_in[11];
    const void* head_w   = d_in[12];
    const void* t0_proj  = d_in[13];
    const void* t0_out   = d_in[14];
    const void* t1_proj  = d_in[15];
    const void* t1_out   = d_in[16];

    float* ws = (float*)d_ws;
    float* embedded = ws + OFF_EMB;
    float* fA    = ws + OFF_FA;
    float* fB    = ws + OFF_FB;
    unsigned short* fAb  = (unsigned short*)(ws + OFF_FAB);
    unsigned short* fBb  = (unsigned short*)(ws + OFF_FBB);
    unsigned short* wgtb = (unsigned short*)(ws + OFF_WGTB);
    float* gates = ws + OFF_GATES;
    float* gih   = ws + OFF_GIH;
    float* ghh   = ws + OFF_GHH;
    float* hdec  = ws + OFF_HDEC;
    unsigned short* hdecb = (unsigned short*)(ws + OFF_HDECB);
    unsigned short* winb  = (unsigned short*)(ws + OFF_WINB);
    unsigned short* hsb   = (unsigned short*)(ws + OFF_HSB);
    unsigned short* p0b   = (unsigned short*)(ws + OFF_P0B);
    unsigned short* p1b   = (unsigned short*)(ws + OFF_P1B);
    float* stats = ws + OFF_STATS;
    float* corr  = ws + OFF_CORR;
    float* lsep  = ws + OFF_LSEP;
    unsigned short* WB = (unsigned short*)(ws + OFF_WB);
    int* flagp = (int*)(ws + OFF_FLAG);
    void* out = d_out;

    k_detect<<<1, 64, 0, stream>>>(G, flagp);

    ConvArgs ca;
    ca.src[0] = enc_w_ih; ca.src[1] = enc_w_hh; ca.src[2] = dec_w_ih;
    ca.src[3] = dec_w_hh; ca.src[4] = head_w;   ca.src[5] = t0_proj;
    ca.src[6] = t1_proj;  ca.src[7] = t0_out;   ca.src[8] = t1_out;
    ca.off[0] = WO_ENCIH; ca.off[1] = WO_ENCHH; ca.off[2] = WO_DECIH;
    ca.off[3] = WO_DECHH; ca.off[4] = WO_W1;
    ca.off[5] = WO_W1 + 2002u * 512u;
    ca.off[6] = WO_W1 + 2130u * 512u;
    ca.off[7] = WO_T0O;   ca.off[8] = WO_T1O;   ca.off[9] = WO_END;
    k_wembed<<<3072, 256, 0, stream>>>(ca, WB, flagp, x, emb, embedded, fA, fAb);

    // encoder layer 0: fA -> fB  (ih + hh fused via gridDim.z)
    {
        GemmP p = defp(lengths, flagp);
        p.A0 = wgtb; p.A1 = fAb; p.W = WB + WO_ENCIH;
        p.w1off = (unsigned long long)(WO_ENCHH - WO_ENCIH);
        p.M = 512; p.N = 1536; p.K = 512;
        p.Zg = gates; p.ldz = 3072; p.zcol1 = 1536;
        p.bias0 = enc_b_ih; p.bias1 = enc_b_hh; p.boff = 0;
        k_wgt<<<1024, 256, 0, stream>>>(G, fA, wgtb, 0, flagp);
        k_gemm0<<<dim3(12, 4, 2), 256, 0, stream>>>(p);
        k_apply_enc<<<1024, 256, 0, stream>>>(gates, fA, fB, fBb);
    }

    // encoder layer 1: fB -> fA
    {
        GemmP p = defp(lengths, flagp);
        p.A0 = wgtb; p.A1 = fBb; p.W = WB + WO_ENCIH + 786432u;
        p.w1off = (unsigned long long)(WO_ENCHH - WO_ENCIH);
        p.M = 512; p.N = 1536; p.K = 512;
        p.Zg = gates; p.ldz = 3072; p.zcol1 = 1536;
        p.bias0 = enc_b_ih; p.bias1 = enc_b_hh; p.boff = 1536;
        k_wgt<<<1024, 256, 0, stream>>>(G, fB, wgtb, 1, flagp);
        k_gemm0<<<dim3(12, 4, 2), 256, 0, stream>>>(p);
        k_apply_enc<<<1024, 256, 0, stream>>>(gates, fB, fA, fAb);
    }

    // decoder prep: h0 + window gather in one launch
    k_h0win<<<5000, 256, 0, stream>>>(embedded, fA, lengths, winb, hdec, hdecb);

    // batched decoder ih GEMM (all 4 d-steps at once)
    {
        GemmP p = defp(lengths, flagp);
        p.A0 = winb; p.W = WB + WO_DECIH;
        p.M = 2000; p.N = 1536; p.K = 512;
        p.Zg = gih; p.ldz = 1536;
        p.bias0 = dec_b_ih; p.boff = 0;
        k_gemm0<<<dim3(12, 16, 1), 256, 0, stream>>>(p);
    }

    // serial decoder hh steps — split-K x4 for occupancy (48 -> 192 blocks)
    for (int d = 0; d < D_; ++d) {
        GemmP p = defp(lengths, flagp);
        p.A0 = hdecb; p.W = WB + WO_DECHH;
        p.M = 500; p.N = 1536; p.K = 512; p.ksplit = 4;
        p.Zg = ghh; p.ldz = 1536;
        p.bias0 = dec_b_hh; p.boff = 0;
        k_gemm0<<<dim3(12, 4, 4), 256, 0, stream>>>(p);
        k_apply_dec<<<1000, 256, 0, stream>>>(gih, ghh, hdec, hdecb, hsb, lengths, d);
    }

    // adaptive softmax — pass A: head (LSE partials + projections)
    {
        GemmP p = defp(lengths, flagp);
        p.A0 = hsb; p.W = WB + WO_W1;
        p.M = NROW_; p.N = NTOTC; p.K = 512; p.Nlse = NH_;
        p.stats = stats; p.p0b = p0b; p.p1b = p1b;
        p.lsep = lsep; p.slotBase = 0;
        k_gemm1<<<dim3(17, 16, 1), 256, 0, stream>>>(p);
    }
    // pass A tails: t0 (63 tiles) + t1 (43 blocks x nrep=4 = 172 tiles) merged
    {
        GemmP pa = defp(lengths, flagp);
        pa.A0 = p0b; pa.W = WB + WO_T0O;
        pa.M = NROW_; pa.N = 8000; pa.K = 128; pa.Nlse = 8000;
        pa.lsep = lsep; pa.slotBase = 17; pa.gx = 63;
        GemmP pb = defp(lengths, flagp);
        pb.A0 = p1b; pb.W = WB + WO_T1O;
        pb.M = NROW_; pb.N = 22000; pb.K = 32; pb.Nlse = 22000;
        pb.lsep = lsep; pb.slotBase = 80; pb.gx = 43; pb.nrep = 4;
        k_gemmA2<<<dim3(106, 16, 1), 256, 0, stream>>>(pa, pb);
    }

    k_corr2<<<8, 256, 0, stream>>>(lsep, stats, corr);

    // pass B: recompute + store corrected log-probs, all 3 segments merged
    {
        GemmP pa = defp(lengths, flagp);
        pa.A0 = hsb; pa.W = WB + WO_W1;
        pa.M = NROW_; pa.N = C0_; pa.K = 512;
        pa.out = out; pa.outColOff = 0; pa.corr = corr; pa.crIdx = 0; pa.gx = 16;
        GemmP pb = defp(lengths, flagp);
        pb.A0 = p0b; pb.W = WB + WO_T0O;
        pb.M = NROW_; pb.N = 8000; pb.K = 128;
        pb.out = out; pb.outColOff = C0_; pb.corr = corr; pb.crIdx = 1; pb.gx = 63;
        GemmP pc = defp(lengths, flagp);
        pc.A0 = p1b; pc.W = WB + WO_T1O;
        pc.M = NROW_; pc.N = 22000; pc.K = 32;
        pc.out = out; pc.outColOff = C1_; pc.corr = corr; pc.crIdx = 2;
        pc.gx = 43; pc.nrep = 4;
        k_gemmB3<<<dim3(122, 16, 1), 256, 0, stream>>>(pa, pb, pc);
    }
}

// Round 2
// 831.561 us; speedup vs baseline: 1.2371x; 1.2371x over previous
//
#include <hip/hip_runtime.h>
#include <hip/hip_bf16.h>
#include <cstring>

typedef __hip_bfloat16 bf16;
typedef __attribute__((ext_vector_type(8))) short short8v;
typedef __attribute__((ext_vector_type(4))) float float4v;

#define V_    32000
#define E_    512
#define H_    512
#define T_    128
#define B_    4
#define D_    4
#define L_    2
#define C0_   2000
#define C1_   10000
#define NT_   125
#define NROW_ 2000          // B*NT*D
#define NH_   2002
#define NTOTC 2162          // 2002 + 128 + 32
#define NSLOT 252           // 17 head + 63 t0 + 172 t1 LSE partial slots per row

__device__ __forceinline__ float bf2f(bf16 v) { return __bfloat162float(v); }
__device__ __forceinline__ unsigned short f2bfu(float f) {
    bf16 h = __float2bfloat16(f);
    union { bf16 h; unsigned short u; } cv; cv.h = h; return cv.u;
}
// dtype-flag helpers: bf==1 -> bf16 input data, bf==0 -> float32
__device__ __forceinline__ float ld1(const void* p, size_t i, int bf) {
    return bf ? bf2f(((const bf16*)p)[i]) : ((const float*)p)[i];
}
__device__ __forceinline__ void st1(void* p, size_t i, int bf, float v) {
    if (bf) ((unsigned short*)p)[i] = f2bfu(v);
    else    ((float*)p)[i] = v;
}

__device__ __forceinline__ void lse_push(float z, float& m, float& s) {
    if (z <= m) { s += __expf(z - m); }
    else        { s = s * __expf(m - z) + 1.0f; m = z; }
}
__device__ __forceinline__ void lse_merge(float m2, float s2, float& m, float& s) {
    float mm = fmaxf(m, m2);
    s = s * __expf(m - mm) + s2 * __expf(m2 - mm);
    m = mm;
}

// ---------------- stage 0: dtype detect (G row 0 is a softmax row) --------
__global__ void k_detect(const void* __restrict__ G, int* __restrict__ flag) {
    int t = threadIdx.x;   // 64 threads
    float s32 = 0.0f;
    for (int k = t; k < 128; k += 64) s32 += ((const float*)G)[k];
    for (int off = 32; off; off >>= 1) s32 += __shfl_down(s32, off);
    if (t == 0) {
        float e32 = fabsf(s32 - 1.0f);
        *flag = (e32 < 0.05f) ? 0 : 1;   // NaN compares false -> bf16 fallback
    }
}

// ---------------- weight conversion + embedding gather (merged) -----------
struct ConvArgs {
    const void* src[9];
    unsigned int off[10];
};
__global__ void k_wembed(ConvArgs a, unsigned short* __restrict__ wb,
                         const int* __restrict__ flagp,
                         const int* __restrict__ x, const void* __restrict__ emb,
                         float* __restrict__ embedded, float* __restrict__ f0,
                         unsigned short* __restrict__ f0b) {
    const int bf = *flagp;
    if (blockIdx.x < 1024) {
        // embedding gather: 262144 elements
        int i = blockIdx.x * 256 + threadIdx.x;
        int bt = i >> 9, e = i & 511;
        int tok = x[bt];
        float v = ld1(emb, (size_t)tok * E_ + e, bf);
        embedded[i] = v; f0[i] = v; f0b[i] = f2bfu(v);
    } else {
        // weight conversion -> contiguous bf16 region (grid-stride)
        unsigned int total = a.off[9];
        unsigned int stride = (gridDim.x - 1024) * 256;
        for (unsigned int i = (blockIdx.x - 1024) * 256 + threadIdx.x; i < total;
             i += stride) {
            int seg = 0;
            while (i >= a.off[seg + 1]) seg++;
            wb[i] = f2bfu(ld1(a.src[seg], i - a.off[seg], bf));
        }
    }
}

// ---------------- wgt[b,i,e] = sum_j G[b,l,j,i] f[b,j,e] ------------------
__global__ void k_wgt(const void* __restrict__ G, const float* __restrict__ f,
                      unsigned short* __restrict__ wgtb, int l,
                      const int* __restrict__ flagp) {
    const int bf = *flagp;
    int i = blockIdx.x * 256 + threadIdx.x;          // 262144
    int e = i & 511;
    int bi = i >> 9;
    int b = bi >> 7, ip = bi & 127;
    size_t gbase = ((size_t)(b * L_ + l) * T_ * T_) + ip;
    const float* fb = f + (size_t)b * T_ * E_ + e;
    float acc = 0.0f;
    #pragma unroll 4
    for (int j = 0; j < T_; ++j)
        acc = fmaf(ld1(G, gbase + (size_t)j * T_, bf), fb[(size_t)j * E_], acc);
    wgtb[i] = f2bfu(acc);
}

// ---------------- MFMA bf16 GEMM core: Z[M,N] = A[M,K] * W[N,K]^T ---------
// MODE 0: gates   (store Z+bias into Zg; blockIdx.z = A/W pair OR K-slice)
// MODE 1: head passA (LSE cols<2002 -> lsep; stats 2000/2001; proj -> p0b/p1b)
// MODE 2: tail passA (LSE over all N -> lsep at slotBase)
// MODE 3: passB (store valid ? z - corr[crIdx] : 0 into out at outColOff)
struct GemmP {
    const unsigned short* A0;
    const unsigned short* A1;
    const unsigned short* W;
    unsigned long long w1off;
    int M, N, K, Nlse;
    float* Zg; int ldz; int zcol1;
    const void* bias0; const void* bias1; int boff;
    void* out; int outColOff;
    float* stats;
    unsigned short* p0b;
    unsigned short* p1b;
    float* lsep; int slotBase;
    const float* corr;
    const int* lengths;
    const int* flagp;
    int gx;       // grid-x width of this segment (for merged dispatch)
    int nrep;     // n-tiles handled per block (amortize per-block overhead)
    int crIdx;    // correction index for MODE 3
    int ksplit;   // split-K factor via blockIdx.z (MODE 0 only)
};

template<int MODE>
__device__ __forceinline__ void gemm_core(const GemmP& p, int bx, int by,
        unsigned short* As, unsigned short* Bs,
        float (*pm)[2], float (*ps)[2]) {
    const int bf = *p.flagp;
    int zsel = 0, kslice = 0;
    if (MODE == 0) {
        if (p.ksplit > 1) kslice = blockIdx.z;
        else              zsel   = blockIdx.z;
    }
    const unsigned short* A  = zsel ? p.A1 : p.A0;
    const unsigned short* Bw = p.W + (zsel ? p.w1off : 0ull);
    const int M = p.M, N = p.N, K = p.K;
    const int m0 = by * 128;
    const int t = threadIdx.x;
    const int wave = t >> 6, lane = t & 63;
    const int wm = wave >> 1, wn = wave & 1;
    const int quad = lane >> 4, l16 = lane & 15;
    const int kcnt = K / p.ksplit;
    const int kbeg = kslice * kcnt;

    for (int nr = 0; nr < p.nrep; ++nr) {
        const int ntile = bx * p.nrep + nr;
        const int n0 = ntile * 128;

        float4v acc[4][4];
        #pragma unroll
        for (int mi = 0; mi < 4; ++mi)
            #pragma unroll
            for (int ni = 0; ni < 4; ++ni)
                acc[mi][ni] = (float4v){0.f, 0.f, 0.f, 0.f};

        for (int kk = 0; kk < kcnt; kk += 32) {
            const int k0 = kbeg + kk;
            if (kk | nr) __syncthreads();
            #pragma unroll
            for (int i = 0; i < 2; ++i) {
                int idx = t + i * 256;
                int row = idx >> 2, seg = idx & 3;
                uint4 av = {0u, 0u, 0u, 0u};
                int gm = m0 + row;
                if (gm < M) av = *(const uint4*)(A + (size_t)gm * K + k0 + seg * 8);
                *(uint4*)(&As[row * 40 + seg * 8]) = av;
                uint4 bv = {0u, 0u, 0u, 0u};
                int gn = n0 + row;
                if (gn < N) bv = *(const uint4*)(Bw + (size_t)gn * K + k0 + seg * 8);
                *(uint4*)(&Bs[row * 40 + seg * 8]) = bv;
            }
            __syncthreads();
            short8v af[4], bfv[4];
            #pragma unroll
            for (int mi = 0; mi < 4; ++mi)
                af[mi] = *(const short8v*)(As + (wm * 64 + mi * 16 + l16) * 40 + quad * 8);
            #pragma unroll
            for (int ni = 0; ni < 4; ++ni)
                bfv[ni] = *(const short8v*)(Bs + (wn * 64 + ni * 16 + l16) * 40 + quad * 8);
            #pragma unroll
            for (int mi = 0; mi < 4; ++mi)
                #pragma unroll
                for (int ni = 0; ni < 4; ++ni)
                    acc[mi][ni] = __builtin_amdgcn_mfma_f32_16x16x32_bf16(
                        af[mi], bfv[ni], acc[mi][ni], 0, 0, 0);
        }

        // ---- epilogue ----
        if (MODE == 0) {
            const void* bias = zsel ? p.bias1 : p.bias0;
            const int zcol = zsel ? p.zcol1 : 0;
            float* Z = p.Zg + (size_t)kslice * p.M * p.ldz;
            #pragma unroll
            for (int mi = 0; mi < 4; ++mi)
                #pragma unroll
                for (int r = 0; r < 4; ++r) {
                    int grow = m0 + wm * 64 + mi * 16 + quad * 4 + r;
                    if (grow >= M) continue;
                    #pragma unroll
                    for (int ni = 0; ni < 4; ++ni) {
                        int gcol = n0 + wn * 64 + ni * 16 + l16;
                        if (gcol < N) {
                            float bv = (kslice == 0) ? ld1(bias, p.boff + gcol, bf) : 0.0f;
                            Z[(size_t)grow * p.ldz + zcol + gcol] = acc[mi][ni][r] + bv;
                        }
                    }
                }
        } else if (MODE == 1) {
            #pragma unroll
            for (int mi = 0; mi < 4; ++mi)
                #pragma unroll
                for (int r = 0; r < 4; ++r) {
                    int grow = m0 + wm * 64 + mi * 16 + quad * 4 + r;
                    if (grow >= M) continue;
                    #pragma unroll
                    for (int ni = 0; ni < 4; ++ni) {
                        int gcol = n0 + wn * 64 + ni * 16 + l16;
                        float v = acc[mi][ni][r];
                        if (gcol >= C0_ && gcol < NH_) p.stats[grow * 8 + 2 + (gcol - C0_)] = v;
                        else if (gcol >= NH_ && gcol < 2130) p.p0b[grow * 128 + (gcol - NH_)] = f2bfu(v);
                        else if (gcol >= 2130 && gcol < NTOTC) p.p1b[grow * 32 + (gcol - 2130)] = f2bfu(v);
                    }
                }
        } else if (MODE == 3) {
            const int crIdx = p.crIdx;
            #pragma unroll
            for (int mi = 0; mi < 4; ++mi)
                #pragma unroll
                for (int r = 0; r < 4; ++r) {
                    int grow = m0 + wm * 64 + mi * 16 + quad * 4 + r;
                    if (grow >= M) continue;
                    int b = grow / 500;
                    int tt = (grow - b * 500) >> 2;
                    bool valid = tt < p.lengths[b];
                    float cr = p.corr[grow * 4 + crIdx];
                    #pragma unroll
                    for (int ni = 0; ni < 4; ++ni) {
                        int gcol = n0 + wn * 64 + ni * 16 + l16;
                        if (gcol < N) {
                            float v = valid ? (acc[mi][ni][r] - cr) : 0.0f;
                            st1(p.out, (size_t)grow * V_ + p.outColOff + gcol, bf, v);
                        }
                    }
                }
        }

        // ---- fused per-tile LSE partials (pass A modes only) ----
        if (MODE == 1 || MODE == 2) {
            const int Nlse = p.Nlse;
            #pragma unroll
            for (int mi = 0; mi < 4; ++mi) {
                #pragma unroll
                for (int r = 0; r < 4; ++r) {
                    float m = -1e30f, s = 0.0f;
                    #pragma unroll
                    for (int ni = 0; ni < 4; ++ni) {
                        int gcol = n0 + wn * 64 + ni * 16 + l16;
                        if (gcol < Nlse) lse_push(acc[mi][ni][r], m, s);
                    }
                    #pragma unroll
                    for (int off = 1; off < 16; off <<= 1) {
                        float m2 = __shfl_xor(m, off), s2 = __shfl_xor(s, off);
                        lse_merge(m2, s2, m, s);
                    }
                    if (l16 == 0) {
                        int rl = wm * 64 + mi * 16 + quad * 4 + r;
                        pm[rl][wn] = m; ps[rl][wn] = s;
                    }
                }
            }
            __syncthreads();
            if (t < 128) {
                int grow = m0 + t;
                if (grow < M) {
                    float m = pm[t][0], s = ps[t][0];
                    lse_merge(pm[t][1], ps[t][1], m, s);
                    float* dst = p.lsep + ((size_t)grow * NSLOT + p.slotBase + ntile) * 2;
                    dst[0] = m; dst[1] = s;
                }
            }
        }
    }
}

// __launch_bounds__(256, 2): 4 waves/block, min 2 waves/EU -> VGPR budget 256.
// Without this the allocator targeted 8 waves/EU (VGPR=64) and spilled the
// 64-VGPR accumulator tile to scratch (round-1 rocprof: WRITE_SIZE 434 MB vs
// 256 MB ideal, FETCH 221 MB vs ~70 MB, MfmaUtil 1.6%).
__global__ __launch_bounds__(256, 2) void k_gemm0(GemmP p) {
    __shared__ __align__(16) unsigned short As[128 * 40];
    __shared__ __align__(16) unsigned short Bs[128 * 40];
    __shared__ float pm[128][2], ps[128][2];
    gemm_core<0>(p, blockIdx.x, blockIdx.y, As, Bs, pm, ps);
}
__global__ __launch_bounds__(256, 2) void k_gemm1(GemmP p) {
    __shared__ __align__(16) unsigned short As[128 * 40];
    __shared__ __align__(16) unsigned short Bs[128 * 40];
    __shared__ float pm[128][2], ps[128][2];
    gemm_core<1>(p, blockIdx.x, blockIdx.y, As, Bs, pm, ps);
}
__global__ __launch_bounds__(256, 2) void k_gemmA2(GemmP pa, GemmP pb) {
    __shared__ __align__(16) unsigned short As[128 * 40];
    __shared__ __align__(16) unsigned short Bs[128 * 40];
    __shared__ float pm[128][2], ps[128][2];
    int bx = blockIdx.x;
    if (bx < pa.gx) gemm_core<2>(pa, bx, blockIdx.y, As, Bs, pm, ps);
    else            gemm_core<2>(pb, bx - pa.gx, blockIdx.y, As, Bs, pm, ps);
}
__global__ __launch_bounds__(256, 2) void k_gemmB3(GemmP pa, GemmP pb, GemmP pc) {
    __shared__ __align__(16) unsigned short As[128 * 40];
    __shared__ __align__(16) unsigned short Bs[128 * 40];
    __shared__ float pm[128][2], ps[128][2];
    int bx = blockIdx.x;
    if (bx < pa.gx)              gemm_core<3>(pa, bx, blockIdx.y, As, Bs, pm, ps);
    else if (bx < pa.gx + pb.gx) gemm_core<3>(pb, bx - pa.gx, blockIdx.y, As, Bs, pm, ps);
    else                         gemm_core<3>(pc, bx - pa.gx - pb.gx, blockIdx.y, As, Bs, pm, ps);
}

// ---------------- GRU pointwise ----------------
__device__ __forceinline__ float gru2(float i_r, float i_z, float i_n,
                                      float h_r, float h_z, float h_n, float h) {
    float r = 1.0f / (1.0f + __expf(-(i_r + h_r)));
    float z = 1.0f / (1.0f + __expf(-(i_z + h_z)));
    float n = tanhf(i_n + r * h_n);
    return (1.0f - z) * n + z * h;
}

__global__ void k_apply_enc(const float* __restrict__ gates,
                            const float* __restrict__ hprev,
                            float* __restrict__ hnext,
                            unsigned short* __restrict__ hnextb) {
    int i = blockIdx.x * 256 + threadIdx.x;          // 262144
    int row = i >> 9, k = i & 511;
    const float* g = gates + (size_t)row * 3072;
    float v = gru2(g[k], g[512 + k], g[1024 + k],
                   g[1536 + k], g[2048 + k], g[2560 + k], hprev[i]);
    hnext[i] = v; hnextb[i] = f2bfu(v);
}

// merged: window gather (1,024,000) + h0 init (256,000)
__global__ void k_h0win(const float* __restrict__ embedded,
                        const float* __restrict__ ffin,
                        const int* __restrict__ lengths,
                        unsigned short* __restrict__ winb,
                        float* __restrict__ hdec,
                        unsigned short* __restrict__ hdecb) {
    int i = blockIdx.x * 256 + threadIdx.x;          // 1,280,000 total
    if (i < 1024000) {
        int e = i & 511;
        int wr = i >> 9;
        int d = wr / 500, row = wr - d * 500;
        int b = row / NT_, t = row - b * NT_;
        int tok = (d == 0 && t == 0) ? (lengths[b] - 1) : (t + d - 1);
        winb[i] = f2bfu(embedded[((size_t)(b * T_ + tok) << 9) + e]);
    } else {
        int j = i - 1024000;                         // 256,000
        int row = j >> 9, e = j & 511;
        int b = row / NT_, t = row - b * NT_;
        float v = ffin[((size_t)(b * T_ + t) << 9) + e];
        hdec[j] = v; hdecb[j] = f2bfu(v);
    }
}

__global__ void k_apply_dec(const float* __restrict__ gih,
                            const float* __restrict__ ghh,
                            float* __restrict__ hdec,
                            unsigned short* __restrict__ hdecb,
                            unsigned short* __restrict__ hsb,
                            const int* __restrict__ lengths, int d) {
    int i = blockIdx.x * 256 + threadIdx.x;          // 256000
    int row = i >> 9, k = i & 511;
    int b = row / NT_, t = row - b * NT_;
    const float* gi = gih + (size_t)(d * 500 + row) * 1536;
    const float* gh = ghh + (size_t)row * 1536;
    // sum the 4 split-K partial gate buffers (bias included in slice 0 only)
    float h_r = 0.f, h_z = 0.f, h_n = 0.f;
    #pragma unroll
    for (int s = 0; s < 4; ++s) {
        const float* g = gh + (size_t)s * 768000;
        h_r += g[k]; h_z += g[512 + k]; h_n += g[1024 + k];
    }
    float hn = gru2(gi[k], gi[512 + k], gi[1024 + k], h_r, h_z, h_n, hdec[i]);
    hdec[i] = hn; hdecb[i] = f2bfu(hn);
    bool valid = (t + d) < lengths[b];
    hsb[(((size_t)row * D_ + d) << 9) + k] = valid ? f2bfu(hn) : (unsigned short)0;
}

// ---------------- combine LSE partials -> per-row corrections -------------
__global__ void k_corr2(const float* __restrict__ lsep, const float* __restrict__ stats,
                        float* __restrict__ corr) {
    int r = blockIdx.x * 256 + threadIdx.x;
    if (r >= NROW_) return;
    const float* P = lsep + (size_t)r * NSLOT * 2;
    float m = -1e30f, s = 0.0f;
    for (int i = 0; i < 17; ++i)  lse_merge(P[2 * i], P[2 * i + 1], m, s);
    float ch = m + logf(s);
    float lp0 = stats[r * 8 + 2] - ch;
    float lp1 = stats[r * 8 + 3] - ch;
    m = -1e30f; s = 0.0f;
    for (int i = 17; i < 80; ++i) lse_merge(P[2 * i], P[2 * i + 1], m, s);
    float ct0 = m + logf(s);
    m = -1e30f; s = 0.0f;
    for (int i = 80; i < 252; ++i) lse_merge(P[2 * i], P[2 * i + 1], m, s);
    float ct1 = m + logf(s);
    corr[r * 4 + 0] = ch;
    corr[r * 4 + 1] = ct0 - lp0;
    corr[r * 4 + 2] = ct1 - lp1;
}

// ---------------- workspace layout (float offsets, 16B aligned) -----------
#define OFF_EMB    0u          // 262144
#define OFF_FA     262144u     // 262144
#define OFF_FB     524288u     // 262144
#define OFF_FAB    786432u     // 131072 (262144 bf16)
#define OFF_FBB    917504u     // 131072
#define OFF_WGTB   1048576u    // 131072
#define OFF_GATES  1179648u    // 512*3072 = 1572864
#define OFF_GIH    2752512u    // 2000*1536 = 3072000
#define OFF_GHH    5824512u    // 4*500*1536 = 3072000 (split-K x4 partials)
#define OFF_HDEC   8896512u    // 256000
#define OFF_HDECB  9152512u    // 128000
#define OFF_WINB   9280512u    // 512000 (1,024,000 bf16)
#define OFF_HSB    9792512u    // 512000 (1,024,000 bf16)
#define OFF_P0B    10304512u   // 128000 (256000 bf16)
#define OFF_P1B    10432512u   // 32000  (64000 bf16)
#define OFF_STATS  10464512u   // 16000
#define OFF_CORR   10480512u   // 8000
#define OFF_LSEP   10488512u   // 1008000
#define OFF_WB     11496512u   // 3776752 (7553504 bf16)
#define OFF_FLAG   15273264u

// bf16 weight region sub-offsets (shorts)
#define WO_ENCIH   0u
#define WO_ENCHH   1572864u
#define WO_DECIH   3145728u
#define WO_DECHH   3932160u
#define WO_W1      4718592u    // head_w rows, t0_proj, t1_proj (2162x512)
#define WO_T0O     5825536u    // 8000x128
#define WO_T1O     6849536u    // 22000x32
#define WO_END     7553504u

static inline GemmP defp(const int* lengths, const int* flagp) {
    GemmP p;
    memset(&p, 0, sizeof(p));
    p.nrep = 1; p.ksplit = 1;
    p.lengths = lengths; p.flagp = flagp;
    return p;
}

extern "C" void kernel_launch(void* const* d_in, const int* in_sizes, int n_in,
                              void* d_out, int out_size, void* d_ws, size_t ws_size,
                              hipStream_t stream) {
    (void)in_sizes; (void)n_in; (void)out_size; (void)ws_size;
    const int*  x        = (const int*)d_in[0];
    const int*  lengths  = (const int*)d_in[1];
    const void* G        = d_in[2];
    const void* emb      = d_in[3];
    const void* enc_w_ih = d_in[4];
    const void* enc_w_hh = d_in[5];
    const void* enc_b_ih = d_in[6];
    const void* enc_b_hh = d_in[7];
    const void* dec_w_ih = d_in[8];
    const void* dec_w_hh = d_in[9];
    const void* dec_b_ih = d_in[10];
    const void* dec_b_hh = d_in[11];
    const void* head_w   = d_in[12];
    const void* t0_proj  = d_in[13];
    const void* t0_out   = d_in[14];
    const void* t1_proj  = d_in[15];
    const void* t1_out   = d_in[16];

    float* ws = (float*)d_ws;
    float* embedded = ws + OFF_EMB;
    float* fA    = ws + OFF_FA;
    float* fB    = ws + OFF_FB;
    unsigned short* fAb  = (unsigned short*)(ws + OFF_FAB);
    unsigned short* fBb  = (unsigned short*)(ws + OFF_FBB);
    unsigned short* wgtb = (unsigned short*)(ws + OFF_WGTB);
    float* gates = ws + OFF_GATES;
    float* gih   = ws + OFF_GIH;
    float* ghh   = ws + OFF_GHH;
    float* hdec  = ws + OFF_HDEC;
    unsigned short* hdecb = (unsigned short*)(ws + OFF_HDECB);
    unsigned short* winb  = (unsigned short*)(ws + OFF_WINB);
    unsigned short* hsb   = (unsigned short*)(ws + OFF_HSB);
    unsigned short* p0b   = (unsigned short*)(ws + OFF_P0B);
    unsigned short* p1b   = (unsigned short*)(ws + OFF_P1B);
    float* stats = ws + OFF_STATS;
    float* corr  = ws + OFF_CORR;
    float* lsep  = ws + OFF_LSEP;
    unsigned short* WB = (unsigned short*)(ws + OFF_WB);
    int* flagp = (int*)(ws + OFF_FLAG);
    void* out = d_out;

    k_detect<<<1, 64, 0, stream>>>(G, flagp);

    ConvArgs ca;
    ca.src[0] = enc_w_ih; ca.src[1] = enc_w_hh; ca.src[2] = dec_w_ih;
    ca.src[3] = dec_w_hh; ca.src[4] = head_w;   ca.src[5] = t0_proj;
    ca.src[6] = t1_proj;  ca.src[7] = t0_out;   ca.src[8] = t1_out;
    ca.off[0] = WO_ENCIH; ca.off[1] = WO_ENCHH; ca.off[2] = WO_DECIH;
    ca.off[3] = WO_DECHH; ca.off[4] = WO_W1;
    ca.off[5] = WO_W1 + 2002u * 512u;
    ca.off[6] = WO_W1 + 2130u * 512u;
    ca.off[7] = WO_T0O;   ca.off[8] = WO_T1O;   ca.off[9] = WO_END;
    k_wembed<<<3072, 256, 0, stream>>>(ca, WB, flagp, x, emb, embedded, fA, fAb);

    // encoder layer 0: fA -> fB  (ih + hh fused via gridDim.z)
    {
        GemmP p = defp(lengths, flagp);
        p.A0 = wgtb; p.A1 = fAb; p.W = WB + WO_ENCIH;
        p.w1off = (unsigned long long)(WO_ENCHH - WO_ENCIH);
        p.M = 512; p.N = 1536; p.K = 512;
        p.Zg = gates; p.ldz = 3072; p.zcol1 = 1536;
        p.bias0 = enc_b_ih; p.bias1 = enc_b_hh; p.boff = 0;
        k_wgt<<<1024, 256, 0, stream>>>(G, fA, wgtb, 0, flagp);
        k_gemm0<<<dim3(12, 4, 2), 256, 0, stream>>>(p);
        k_apply_enc<<<1024, 256, 0, stream>>>(gates, fA, fB, fBb);
    }

    // encoder layer 1: fB -> fA
    {
        GemmP p = defp(lengths, flagp);
        p.A0 = wgtb; p.A1 = fBb; p.W = WB + WO_ENCIH + 786432u;
        p.w1off = (unsigned long long)(WO_ENCHH - WO_ENCIH);
        p.M = 512; p.N = 1536; p.K = 512;
        p.Zg = gates; p.ldz = 3072; p.zcol1 = 1536;
        p.bias0 = enc_b_ih; p.bias1 = enc_b_hh; p.boff = 1536;
        k_wgt<<<1024, 256, 0, stream>>>(G, fB, wgtb, 1, flagp);
        k_gemm0<<<dim3(12, 4, 2), 256, 0, stream>>>(p);
        k_apply_enc<<<1024, 256, 0, stream>>>(gates, fB, fA, fAb);
    }

    // decoder prep: h0 + window gather in one launch
    k_h0win<<<5000, 256, 0, stream>>>(embedded, fA, lengths, winb, hdec, hdecb);

    // batched decoder ih GEMM (all 4 d-steps at once)
    {
        GemmP p = defp(lengths, flagp);
        p.A0 = winb; p.W = WB + WO_DECIH;
        p.M = 2000; p.N = 1536; p.K = 512;
        p.Zg = gih; p.ldz = 1536;
        p.bias0 = dec_b_ih; p.boff = 0;
        k_gemm0<<<dim3(12, 16, 1), 256, 0, stream>>>(p);
    }

    // serial decoder hh steps — split-K x4 for occupancy (48 -> 192 blocks)
    for (int d = 0; d < D_; ++d) {
        GemmP p = defp(lengths, flagp);
        p.A0 = hdecb; p.W = WB + WO_DECHH;
        p.M = 500; p.N = 1536; p.K = 512; p.ksplit = 4;
        p.Zg = ghh; p.ldz = 1536;
        p.bias0 = dec_b_hh; p.boff = 0;
        k_gemm0<<<dim3(12, 4, 4), 256, 0, stream>>>(p);
        k_apply_dec<<<1000, 256, 0, stream>>>(gih, ghh, hdec, hdecb, hsb, lengths, d);
    }

    // adaptive softmax — pass A: head (LSE partials + projections)
    {
        GemmP p = defp(lengths, flagp);
        p.A0 = hsb; p.W = WB + WO_W1;
        p.M = NROW_; p.N = NTOTC; p.K = 512; p.Nlse = NH_;
        p.stats = stats; p.p0b = p0b; p.p1b = p1b;
        p.lsep = lsep; p.slotBase = 0;
        k_gemm1<<<dim3(17, 16, 1), 256, 0, stream>>>(p);
    }
    // pass A tails: t0 (63 tiles) + t1 (43 blocks x nrep=4 = 172 tiles) merged
    {
        GemmP pa = defp(lengths, flagp);
        pa.A0 = p0b; pa.W = WB + WO_T0O;
        pa.M = NROW_; pa.N = 8000; pa.K = 128; pa.Nlse = 8000;
        pa.lsep = lsep; pa.slotBase = 17; pa.gx = 63;
        GemmP pb = defp(lengths, flagp);
        pb.A0 = p1b; pb.W = WB + WO_T1O;
        pb.M = NROW_; pb.N = 22000; pb.K = 32; pb.Nlse = 22000;
        pb.lsep = lsep; pb.slotBase = 80; pb.gx = 43; pb.nrep = 4;
        k_gemmA2<<<dim3(106, 16, 1), 256, 0, stream>>>(pa, pb);
    }

    k_corr2<<<8, 256, 0, stream>>>(lsep, stats, corr);

    // pass B: recompute + store corrected log-probs, all 3 segments merged
    {
        GemmP pa = defp(lengths, flagp);
        pa.A0 = hsb; pa.W = WB + WO_W1;
        pa.M = NROW_; pa.N = C0_; pa.K = 512;
        pa.out = out; pa.outColOff = 0; pa.corr = corr; pa.crIdx = 0; pa.gx = 16;
        GemmP pb = defp(lengths, flagp);
        pb.A0 = p0b; pb.W = WB + WO_T0O;
        pb.M = NROW_; pb.N = 8000; pb.K = 128;
        pb.out = out; pb.outColOff = C0_; pb.corr = corr; pb.crIdx = 1; pb.gx = 63;
        GemmP pc = defp(lengths, flagp);
        pc.A0 = p1b; pc.W = WB + WO_T1O;
        pc.M = NROW_; pc.N = 22000; pc.K = 32;
        pc.out = out; pc.outColOff = C1_; pc.corr = corr; pc.crIdx = 2;
        pc.gx = 43; pc.nrep = 4;
        k_gemmB3<<<dim3(122, 16, 1), 256, 0, stream>>>(pa, pb, pc);
    }
}

// Round 4
// 783.927 us; speedup vs baseline: 1.3123x; 1.0608x over previous
//
#include <hip/hip_runtime.h>
#include <hip/hip_bf16.h>
#include <hip/hip_fp16.h>

typedef __hip_bfloat16 bf16;
typedef __attribute__((ext_vector_type(8))) short short8v;
typedef __attribute__((ext_vector_type(4))) float float4v;

#define V_    32000
#define E_    512
#define H_    512
#define T_    128
#define B_    4
#define D_    4
#define L_    2
#define C0_   2000
#define C1_   10000
#define NT_   125
#define NROW_ 2000          // B*NT*D
#define NH_   2002
#define NTOTC 2162          // 2002 + 128 + 32
#define NSLOT 252           // 17 head + 63 t0 + 172 t1 LSE partial slots per row

__device__ __forceinline__ float bf2f(bf16 v) { return __bfloat162float(v); }
__device__ __forceinline__ unsigned short f2bfu(float f) {
    bf16 h = __float2bfloat16(f);
    union { bf16 h; unsigned short u; } cv; cv.h = h; return cv.u;
}
// dtype-flag helpers: bf==1 -> bf16 input data, bf==0 -> float32
__device__ __forceinline__ float ld1(const void* p, size_t i, int bf) {
    return bf ? bf2f(((const bf16*)p)[i]) : ((const float*)p)[i];
}

__device__ __forceinline__ void lse_push(float z, float& m, float& s) {
    if (z <= m) { s += __expf(z - m); }
    else        { s = s * __expf(m - z) + 1.0f; m = z; }
}
__device__ __forceinline__ void lse_merge(float m2, float s2, float& m, float& s) {
    float mm = fmaxf(m, m2);
    s = s * __expf(m - mm) + s2 * __expf(m2 - mm);
    m = mm;
}

// ---------------- stage 0: dtype detect (G row 0 is a softmax row) --------
__global__ void k_detect(const void* __restrict__ G, int* __restrict__ flag) {
    int t = threadIdx.x;   // 64 threads
    float s32 = 0.0f;
    for (int k = t; k < 128; k += 64) s32 += ((const float*)G)[k];
    for (int off = 32; off; off >>= 1) s32 += __shfl_down(s32, off);
    if (t == 0) {
        float e32 = fabsf(s32 - 1.0f);
        *flag = (e32 < 0.05f) ? 0 : 1;   // NaN compares false -> bf16 fallback
    }
}

// ---------------- weight conversion + embedding gather (merged) -----------
struct ConvArgs {
    const void* src[9];
    unsigned int off[10];
};
__global__ void k_wembed(ConvArgs a, unsigned short* __restrict__ wb,
                         const int* __restrict__ flagp,
                         const int* __restrict__ x, const void* __restrict__ emb,
                         float* __restrict__ embedded, float* __restrict__ f0,
                         unsigned short* __restrict__ f0b) {
    const int bf = *flagp;
    if (blockIdx.x < 1024) {
        // embedding gather: 262144 elements
        int i = blockIdx.x * 256 + threadIdx.x;
        int bt = i >> 9, e = i & 511;
        int tok = x[bt];
        float v = ld1(emb, (size_t)tok * E_ + e, bf);
        embedded[i] = v; f0[i] = v; f0b[i] = f2bfu(v);
    } else {
        // weight conversion -> contiguous bf16 region (grid-stride)
        unsigned int total = a.off[9];
        unsigned int stride = (gridDim.x - 1024) * 256;
        for (unsigned int i = (blockIdx.x - 1024) * 256 + threadIdx.x; i < total;
             i += stride) {
            int seg = 0;
            while (i >= a.off[seg + 1]) seg++;
            wb[i] = f2bfu(ld1(a.src[seg], i - a.off[seg], bf));
        }
    }
}

// ---------------- wgt[b,i,e] = sum_j G[b,l,j,i] f[b,j,e] ------------------
__global__ void k_wgt(const void* __restrict__ G, const float* __restrict__ f,
                      unsigned short* __restrict__ wgtb, int l,
                      const int* __restrict__ flagp) {
    const int bf = *flagp;
    int i = blockIdx.x * 256 + threadIdx.x;          // 262144
    int e = i & 511;
    int bi = i >> 9;
    int b = bi >> 7, ip = bi & 127;
    size_t gbase = ((size_t)(b * L_ + l) * T_ * T_) + ip;
    const float* fb = f + (size_t)b * T_ * E_ + e;
    float acc = 0.0f;
    #pragma unroll 4
    for (int j = 0; j < T_; ++j)
        acc = fmaf(ld1(G, gbase + (size_t)j * T_, bf), fb[(size_t)j * E_], acc);
    wgtb[i] = f2bfu(acc);
}

// ---------------- MFMA bf16 GEMM: Z[M,N] = A[M,K] * W[N,K]^T --------------
// MODE 0: gates   (store Z+bias into Zg at col zsel*zcol1; blockIdx.z picks A/W/bias)
// MODE 1: head single-pass (raw z -> out-in-place for cols<C0; LSE cols<2002 -> lsep;
//         stats 2000/2001; proj -> p0b/p1b)
// MODE 2: tail single-pass (raw z -> out-in-place at outColOff; LSE over all N)
// Raw-logit staging format: fp16 when final out dtype is bf16 (2B slots),
// fp32 when final out dtype is fp32 (4B slots) — d_out is exactly the right
// size in both modes, so no extra workspace and no flag-clobber hazard.
struct GemmP {
    const unsigned short* A0;
    const unsigned short* A1;
    const unsigned short* W;
    unsigned long long w1off;
    int M, N, K, Nlse;
    float* Zg; int ldz; int zcol1;
    const void* bias0; const void* bias1; int boff;
    void* zraw; int outColOff;
    float* stats;
    unsigned short* p0b;
    unsigned short* p1b;
    float* lsep; int slotBase;
    const int* lengths;
    const int* flagp;
};

__device__ __forceinline__ void zstore(void* zraw, size_t i, int bf, float v) {
    if (bf) ((__half*)zraw)[i] = __float2half(v);
    else    ((float*)zraw)[i]  = v;
}

// __launch_bounds__(256, 2): 4 waves/block, min 2 waves/EU -> VGPR cap 256.
// Insurance against the r1 allocator heuristic that targeted 8 waves/EU
// (VGPR=64) and spilled the 64-VGPR accumulator tile to scratch.
template<int MODE>
__global__ __launch_bounds__(256, 2) void k_gemm(GemmP p) {
    const int bf = *p.flagp;
    const int zsel = (MODE == 0) ? blockIdx.z : 0;
    const unsigned short* A  = zsel ? p.A1 : p.A0;
    const unsigned short* Bw = p.W + (zsel ? p.w1off : 0ull);
    const int M = p.M, N = p.N, K = p.K;
    const int bx = blockIdx.x, by = blockIdx.y;
    const int m0 = by * 128, n0 = bx * 128;
    const int t = threadIdx.x;
    const int wave = t >> 6, lane = t & 63;
    const int wm = wave >> 1, wn = wave & 1;
    const int quad = lane >> 4, l16 = lane & 15;

    __shared__ __align__(16) unsigned short As[128 * 40];
    __shared__ __align__(16) unsigned short Bs[128 * 40];
    __shared__ float pm[128][2], ps[128][2];

    float4v acc[4][4];
    #pragma unroll
    for (int mi = 0; mi < 4; ++mi)
        #pragma unroll
        for (int ni = 0; ni < 4; ++ni)
            acc[mi][ni] = (float4v){0.f, 0.f, 0.f, 0.f};

    for (int k0 = 0; k0 < K; k0 += 32) {
        if (k0) __syncthreads();
        #pragma unroll
        for (int i = 0; i < 2; ++i) {
            int idx = t + i * 256;
            int row = idx >> 2, seg = idx & 3;
            uint4 av = {0u, 0u, 0u, 0u};
            int gm = m0 + row;
            if (gm < M) av = *(const uint4*)(A + (size_t)gm * K + k0 + seg * 8);
            *(uint4*)(&As[row * 40 + seg * 8]) = av;
            uint4 bv = {0u, 0u, 0u, 0u};
            int gn = n0 + row;
            if (gn < N) bv = *(const uint4*)(Bw + (size_t)gn * K + k0 + seg * 8);
            *(uint4*)(&Bs[row * 40 + seg * 8]) = bv;
        }
        __syncthreads();
        short8v af[4], bfv[4];
        #pragma unroll
        for (int mi = 0; mi < 4; ++mi)
            af[mi] = *(const short8v*)(As + (wm * 64 + mi * 16 + l16) * 40 + quad * 8);
        #pragma unroll
        for (int ni = 0; ni < 4; ++ni)
            bfv[ni] = *(const short8v*)(Bs + (wn * 64 + ni * 16 + l16) * 40 + quad * 8);
        #pragma unroll
        for (int mi = 0; mi < 4; ++mi)
            #pragma unroll
            for (int ni = 0; ni < 4; ++ni)
                acc[mi][ni] = __builtin_amdgcn_mfma_f32_16x16x32_bf16(
                    af[mi], bfv[ni], acc[mi][ni], 0, 0, 0);
    }

    // ---- epilogue ----
    if (MODE == 0) {
        const void* bias = zsel ? p.bias1 : p.bias0;
        const int zcol = zsel ? p.zcol1 : 0;
        #pragma unroll
        for (int mi = 0; mi < 4; ++mi)
            #pragma unroll
            for (int r = 0; r < 4; ++r) {
                int grow = m0 + wm * 64 + mi * 16 + quad * 4 + r;
                if (grow >= M) continue;
                #pragma unroll
                for (int ni = 0; ni < 4; ++ni) {
                    int gcol = n0 + wn * 64 + ni * 16 + l16;
                    if (gcol < N)
                        p.Zg[(size_t)grow * p.ldz + zcol + gcol] =
                            acc[mi][ni][r] + ld1(bias, p.boff + gcol, bf);
                }
            }
    } else if (MODE == 1) {
        #pragma unroll
        for (int mi = 0; mi < 4; ++mi)
            #pragma unroll
            for (int r = 0; r < 4; ++r) {
                int grow = m0 + wm * 64 + mi * 16 + quad * 4 + r;
                if (grow >= M) continue;
                #pragma unroll
                for (int ni = 0; ni < 4; ++ni) {
                    int gcol = n0 + wn * 64 + ni * 16 + l16;
                    float v = acc[mi][ni][r];
                    if (gcol < C0_) zstore(p.zraw, (size_t)grow * V_ + gcol, bf, v);
                    else if (gcol < NH_) p.stats[grow * 8 + 2 + (gcol - C0_)] = v;
                    else if (gcol < 2130) p.p0b[grow * 128 + (gcol - NH_)] = f2bfu(v);
                    else if (gcol < NTOTC) p.p1b[grow * 32 + (gcol - 2130)] = f2bfu(v);
                }
            }
    } else {
        #pragma unroll
        for (int mi = 0; mi < 4; ++mi)
            #pragma unroll
            for (int r = 0; r < 4; ++r) {
                int grow = m0 + wm * 64 + mi * 16 + quad * 4 + r;
                if (grow >= M) continue;
                #pragma unroll
                for (int ni = 0; ni < 4; ++ni) {
                    int gcol = n0 + wn * 64 + ni * 16 + l16;
                    if (gcol < N)
                        zstore(p.zraw, (size_t)grow * V_ + p.outColOff + gcol, bf,
                               acc[mi][ni][r]);
                }
            }
    }

    // ---- fused per-tile LSE partials (single-pass modes) ----
    if (MODE == 1 || MODE == 2) {
        const int Nlse = p.Nlse;
        #pragma unroll
        for (int mi = 0; mi < 4; ++mi) {
            #pragma unroll
            for (int r = 0; r < 4; ++r) {
                float m = -1e30f, s = 0.0f;
                #pragma unroll
                for (int ni = 0; ni < 4; ++ni) {
                    int gcol = n0 + wn * 64 + ni * 16 + l16;
                    if (gcol < Nlse) lse_push(acc[mi][ni][r], m, s);
                }
                #pragma unroll
                for (int off = 1; off < 16; off <<= 1) {
                    float m2 = __shfl_xor(m, off), s2 = __shfl_xor(s, off);
                    lse_merge(m2, s2, m, s);
                }
                if (l16 == 0) {
                    int rl = wm * 64 + mi * 16 + quad * 4 + r;
                    pm[rl][wn] = m; ps[rl][wn] = s;
                }
            }
        }
        __syncthreads();
        if (t < 128) {
            int grow = m0 + t;
            if (grow < M) {
                float m = pm[t][0], s = ps[t][0];
                lse_merge(pm[t][1], ps[t][1], m, s);
                float* dst = p.lsep + ((size_t)grow * NSLOT + p.slotBase + bx) * 2;
                dst[0] = m; dst[1] = s;
            }
        }
    }
}

// ---------------- GRU pointwise ----------------
__device__ __forceinline__ float gru2(float i_r, float i_z, float i_n,
                                      float h_r, float h_z, float h_n, float h) {
    float r = 1.0f / (1.0f + __expf(-(i_r + h_r)));
    float z = 1.0f / (1.0f + __expf(-(i_z + h_z)));
    float n = tanhf(i_n + r * h_n);
    return (1.0f - z) * n + z * h;
}

__global__ void k_apply_enc(const float* __restrict__ gates,
                            const float* __restrict__ hprev,
                            float* __restrict__ hnext,
                            unsigned short* __restrict__ hnextb) {
    int i = blockIdx.x * 256 + threadIdx.x;          // 262144
    int row = i >> 9, k = i & 511;
    const float* g = gates + (size_t)row * 3072;
    float v = gru2(g[k], g[512 + k], g[1024 + k],
                   g[1536 + k], g[2048 + k], g[2560 + k], hprev[i]);
    hnext[i] = v; hnextb[i] = f2bfu(v);
}

// merged: window gather (1,024,000) + h0 init (256,000)
__global__ void k_h0win(const float* __restrict__ embedded,
                        const float* __restrict__ ffin,
                        const int* __restrict__ lengths,
                        unsigned short* __restrict__ winb,
                        float* __restrict__ hdec,
                        unsigned short* __restrict__ hdecb) {
    int i = blockIdx.x * 256 + threadIdx.x;          // 1,280,000 total
    if (i < 1024000) {
        int e = i & 511;
        int wr = i >> 9;
        int d = wr / 500, row = wr - d * 500;
        int b = row / NT_, t = row - b * NT_;
        int tok = (d == 0 && t == 0) ? (lengths[b] - 1) : (t + d - 1);
        winb[i] = f2bfu(embedded[((size_t)(b * T_ + tok) << 9) + e]);
    } else {
        int j = i - 1024000;                         // 256,000
        int row = j >> 9, e = j & 511;
        int b = row / NT_, t = row - b * NT_;
        float v = ffin[((size_t)(b * T_ + t) << 9) + e];
        hdec[j] = v; hdecb[j] = f2bfu(v);
    }
}

__global__ void k_apply_dec(const float* __restrict__ gih,
                            const float* __restrict__ ghh,
                            float* __restrict__ hdec,
                            unsigned short* __restrict__ hdecb,
                            unsigned short* __restrict__ hsb,
                            const int* __restrict__ lengths, int d) {
    int i = blockIdx.x * 256 + threadIdx.x;          // 256000
    int row = i >> 9, k = i & 511;
    int b = row / NT_, t = row - b * NT_;
    const float* gi = gih + (size_t)(d * 500 + row) * 1536;
    const float* gh = ghh + (size_t)row * 1536;
    float hn = gru2(gi[k], gi[512 + k], gi[1024 + k],
                    gh[k], gh[512 + k], gh[1024 + k], hdec[i]);
    hdec[i] = hn; hdecb[i] = f2bfu(hn);
    bool valid = (t + d) < lengths[b];
    hsb[(((size_t)row * D_ + d) << 9) + k] = valid ? f2bfu(hn) : (unsigned short)0;
}

// ---------------- combine LSE partials -> per-row corrections -------------
__global__ void k_corr2(const float* __restrict__ lsep, const float* __restrict__ stats,
                        float* __restrict__ corr) {
    int r = blockIdx.x * 256 + threadIdx.x;
    if (r >= NROW_) return;
    const float* P = lsep + (size_t)r * NSLOT * 2;
    float m = -1e30f, s = 0.0f;
    for (int i = 0; i < 17; ++i)  lse_merge(P[2 * i], P[2 * i + 1], m, s);
    float ch = m + logf(s);
    float lp0 = stats[r * 8 + 2] - ch;
    float lp1 = stats[r * 8 + 3] - ch;
    m = -1e30f; s = 0.0f;
    for (int i = 17; i < 80; ++i) lse_merge(P[2 * i], P[2 * i + 1], m, s);
    float ct0 = m + logf(s);
    m = -1e30f; s = 0.0f;
    for (int i = 80; i < 252; ++i) lse_merge(P[2 * i], P[2 * i + 1], m, s);
    float ct1 = m + logf(s);
    corr[r * 4 + 0] = ch;
    corr[r * 4 + 1] = ct0 - lp0;
    corr[r * 4 + 2] = ct1 - lp1;
}

// ------ in-place fixup: out[i] = valid ? zraw[i] - corr[seg] : 0 ----------
// Raw logits were staged into d_out itself (fp16 slots when out is bf16,
// fp32 slots when out is fp32). Each thread owns a disjoint 16/32-byte
// group (8 cols); segment boundaries 2000/10000 are multiples of 8 so a
// group never straddles segments. Per-thread read-then-write, no hazards.
__global__ void k_fix(const float* __restrict__ corr,
                      const int* __restrict__ lengths, void* __restrict__ out,
                      const int* __restrict__ flagp) {
    const int bf = *flagp;
    int idx = blockIdx.x * 256 + threadIdx.x;        // 8,000,000 groups
    if (idx >= NROW_ * (V_ / 8)) return;
    int row = idx / (V_ / 8);
    int col = (idx - row * (V_ / 8)) * 8;
    int b = row / 500;
    int tt = (row - b * 500) >> 2;
    bool valid = tt < lengths[b];
    int cri = (col < C0_) ? 0 : (col < C1_ ? 1 : 2);
    float cr = corr[row * 4 + cri];
    size_t base = (size_t)row * V_ + col;
    if (bf) {
        unsigned short* p16 = (unsigned short*)out + base;
        union { uint4 u; __half h[8]; } in;
        in.u = *(const uint4*)p16;
        union { uint4 u; unsigned short s[8]; } o;
        #pragma unroll
        for (int j = 0; j < 8; ++j)
            o.s[j] = f2bfu(valid ? (__half2float(in.h[j]) - cr) : 0.0f);
        *(uint4*)p16 = o.u;
    } else {
        float* op = (float*)out + base;
        float4 a = *(float4*)op, c = *(float4*)(op + 4);
        float4 ra = valid ? (float4){a.x - cr, a.y - cr, a.z - cr, a.w - cr}
                          : (float4){0.f, 0.f, 0.f, 0.f};
        float4 rc = valid ? (float4){c.x - cr, c.y - cr, c.z - cr, c.w - cr}
                          : (float4){0.f, 0.f, 0.f, 0.f};
        *(float4*)op = ra; *(float4*)(op + 4) = rc;
    }
}

// ---------------- workspace layout (float offsets, 16B aligned) -----------
#define OFF_EMB    0u          // 262144
#define OFF_FA     262144u     // 262144
#define OFF_FB     524288u     // 262144
#define OFF_FAB    786432u     // 131072 (262144 bf16)
#define OFF_FBB    917504u     // 131072
#define OFF_WGTB   1048576u    // 131072
#define OFF_GATES  1179648u    // 512*3072 = 1572864
#define OFF_GIH    2752512u    // 2000*1536 = 3072000
#define OFF_GHH    5824512u    // 500*1536 = 768000
#define OFF_HDEC   6592512u    // 256000
#define OFF_HDECB  6848512u    // 128000
#define OFF_WINB   6976512u    // 512000 (1,024,000 bf16)
#define OFF_HSB    7488512u    // 512000 (1,024,000 bf16)
#define OFF_P0B    8000512u    // 128000 (256000 bf16)
#define OFF_P1B    8128512u    // 32000  (64000 bf16)
#define OFF_STATS  8160512u    // 16000
#define OFF_CORR   8176512u    // 8000
#define OFF_LSEP   8184512u    // 1008000
#define OFF_WB     9192512u    // 3776752 (7553504 bf16)
#define OFF_FLAG   12969264u

// bf16 weight region sub-offsets (shorts)
#define WO_ENCIH   0u
#define WO_ENCHH   1572864u
#define WO_DECIH   3145728u
#define WO_DECHH   3932160u
#define WO_W1      4718592u    // head_w rows, t0_proj, t1_proj (2162x512)
#define WO_T0O     5825536u    // 8000x128
#define WO_T1O     6849536u    // 22000x32
#define WO_END     7553504u

static inline GemmP mkp(const unsigned short* A0, const unsigned short* A1,
                        const unsigned short* W, unsigned long long w1off,
                        int M, int N, int K, int Nlse,
                        float* Zg, int ldz, int zcol1,
                        const void* bias0, const void* bias1, int boff,
                        void* zraw, int outColOff, float* stats,
                        unsigned short* p0b, unsigned short* p1b,
                        float* lsep, int slotBase,
                        const int* lengths, const int* flagp) {
    GemmP p;
    p.A0 = A0; p.A1 = A1; p.W = W; p.w1off = w1off;
    p.M = M; p.N = N; p.K = K; p.Nlse = Nlse;
    p.Zg = Zg; p.ldz = ldz; p.zcol1 = zcol1;
    p.bias0 = bias0; p.bias1 = bias1; p.boff = boff;
    p.zraw = zraw; p.outColOff = outColOff; p.stats = stats;
    p.p0b = p0b; p.p1b = p1b; p.lsep = lsep; p.slotBase = slotBase;
    p.lengths = lengths; p.flagp = flagp;
    return p;
}

extern "C" void kernel_launch(void* const* d_in, const int* in_sizes, int n_in,
                              void* d_out, int out_size, void* d_ws, size_t ws_size,
                              hipStream_t stream) {
    (void)in_sizes; (void)n_in; (void)out_size; (void)ws_size;
    const int*  x        = (const int*)d_in[0];
    const int*  lengths  = (const int*)d_in[1];
    const void* G        = d_in[2];
    const void* emb      = d_in[3];
    const void* enc_w_ih = d_in[4];
    const void* enc_w_hh = d_in[5];
    const void* enc_b_ih = d_in[6];
    const void* enc_b_hh = d_in[7];
    const void* dec_w_ih = d_in[8];
    const void* dec_w_hh = d_in[9];
    const void* dec_b_ih = d_in[10];
    const void* dec_b_hh = d_in[11];
    const void* head_w   = d_in[12];
    const void* t0_proj  = d_in[13];
    const void* t0_out   = d_in[14];
    const void* t1_proj  = d_in[15];
    const void* t1_out   = d_in[16];

    float* ws = (float*)d_ws;
    float* embedded = ws + OFF_EMB;
    float* fA    = ws + OFF_FA;
    float* fB    = ws + OFF_FB;
    unsigned short* fAb  = (unsigned short*)(ws + OFF_FAB);
    unsigned short* fBb  = (unsigned short*)(ws + OFF_FBB);
    unsigned short* wgtb = (unsigned short*)(ws + OFF_WGTB);
    float* gates = ws + OFF_GATES;
    float* gih   = ws + OFF_GIH;
    float* ghh   = ws + OFF_GHH;
    float* hdec  = ws + OFF_HDEC;
    unsigned short* hdecb = (unsigned short*)(ws + OFF_HDECB);
    unsigned short* winb  = (unsigned short*)(ws + OFF_WINB);
    unsigned short* hsb   = (unsigned short*)(ws + OFF_HSB);
    unsigned short* p0b   = (unsigned short*)(ws + OFF_P0B);
    unsigned short* p1b   = (unsigned short*)(ws + OFF_P1B);
    float* stats = ws + OFF_STATS;
    float* corr  = ws + OFF_CORR;
    float* lsep  = ws + OFF_LSEP;
    unsigned short* WB = (unsigned short*)(ws + OFF_WB);
    int* flagp = (int*)(ws + OFF_FLAG);
    void* out = d_out;

    k_detect<<<1, 64, 0, stream>>>(G, flagp);

    ConvArgs ca;
    ca.src[0] = enc_w_ih; ca.src[1] = enc_w_hh; ca.src[2] = dec_w_ih;
    ca.src[3] = dec_w_hh; ca.src[4] = head_w;   ca.src[5] = t0_proj;
    ca.src[6] = t1_proj;  ca.src[7] = t0_out;   ca.src[8] = t1_out;
    ca.off[0] = WO_ENCIH; ca.off[1] = WO_ENCHH; ca.off[2] = WO_DECIH;
    ca.off[3] = WO_DECHH; ca.off[4] = WO_W1;
    ca.off[5] = WO_W1 + 2002u * 512u;
    ca.off[6] = WO_W1 + 2130u * 512u;
    ca.off[7] = WO_T0O;   ca.off[8] = WO_T1O;   ca.off[9] = WO_END;
    k_wembed<<<3072, 256, 0, stream>>>(ca, WB, flagp, x, emb, embedded, fA, fAb);

    // encoder layer 0: fA -> fB  (ih + hh fused via gridDim.z)
    k_wgt<<<1024, 256, 0, stream>>>(G, fA, wgtb, 0, flagp);
    k_gemm<0><<<dim3(12, 4, 2), 256, 0, stream>>>(mkp(
        wgtb, fAb, WB + WO_ENCIH, (unsigned long long)(WO_ENCHH - WO_ENCIH),
        512, 1536, 512, 0, gates, 3072, 1536, enc_b_ih, enc_b_hh, 0,
        nullptr, 0, nullptr, nullptr, nullptr, nullptr, 0, lengths, flagp));
    k_apply_enc<<<1024, 256, 0, stream>>>(gates, fA, fB, fBb);

    // encoder layer 1: fB -> fA
    k_wgt<<<1024, 256, 0, stream>>>(G, fB, wgtb, 1, flagp);
    k_gemm<0><<<dim3(12, 4, 2), 256, 0, stream>>>(mkp(
        wgtb, fBb, WB + WO_ENCIH + 786432u, (unsigned long long)(WO_ENCHH - WO_ENCIH),
        512, 1536, 512, 0, gates, 3072, 1536, enc_b_ih, enc_b_hh, 1536,
        nullptr, 0, nullptr, nullptr, nullptr, nullptr, 0, lengths, flagp));
    k_apply_enc<<<1024, 256, 0, stream>>>(gates, fB, fA, fAb);

    // decoder prep: h0 + window gather in one launch
    k_h0win<<<5000, 256, 0, stream>>>(embedded, fA, lengths, winb, hdec, hdecb);

    // batched decoder ih GEMM (all 4 d-steps at once)
    k_gemm<0><<<dim3(12, 16, 1), 256, 0, stream>>>(mkp(
        winb, nullptr, WB + WO_DECIH, 0ull, 2000, 1536, 512, 0,
        gih, 1536, 0, dec_b_ih, nullptr, 0,
        nullptr, 0, nullptr, nullptr, nullptr, nullptr, 0, lengths, flagp));

    // serial decoder hh steps
    for (int d = 0; d < D_; ++d) {
        k_gemm<0><<<dim3(12, 4, 1), 256, 0, stream>>>(mkp(
            hdecb, nullptr, WB + WO_DECHH, 0ull, 500, 1536, 512, 0,
            ghh, 1536, 0, dec_b_hh, nullptr, 0,
            nullptr, 0, nullptr, nullptr, nullptr, nullptr, 0, lengths, flagp));
        k_apply_dec<<<1000, 256, 0, stream>>>(gih, ghh, hdec, hdecb, hsb, lengths, d);
    }

    // adaptive softmax — single pass: raw logits (into out) + LSE partials
    k_gemm<1><<<dim3(17, 16, 1), 256, 0, stream>>>(mkp(
        hsb, nullptr, WB + WO_W1, 0ull, NROW_, NTOTC, 512, NH_,
        nullptr, 0, 0, nullptr, nullptr, 0, out, 0,
        stats, p0b, p1b, lsep, 0, lengths, flagp));
    k_gemm<2><<<dim3(63, 16, 1), 256, 0, stream>>>(mkp(
        p0b, nullptr, WB + WO_T0O, 0ull, NROW_, 8000, 128, 8000,
        nullptr, 0, 0, nullptr, nullptr, 0, out, C0_,
        stats, nullptr, nullptr, lsep, 17, lengths, flagp));
    k_gemm<2><<<dim3(172, 16, 1), 256, 0, stream>>>(mkp(
        p1b, nullptr, WB + WO_T1O, 0ull, NROW_, 22000, 32, 22000,
        nullptr, 0, 0, nullptr, nullptr, 0, out, C1_,
        stats, nullptr, nullptr, lsep, 80, lengths, flagp));

    k_corr2<<<8, 256, 0, stream>>>(lsep, stats, corr);

    // in-place fixup: out = valid ? z - corr : 0  (replaces pass-B GEMMs)
    k_fix<<<31250, 256, 0, stream>>>(corr, lengths, out, flagp);
}

// Round 5
// 765.603 us; speedup vs baseline: 1.3437x; 1.0239x over previous
//
#include <hip/hip_runtime.h>
#include <hip/hip_bf16.h>
#include <hip/hip_fp16.h>

typedef __hip_bfloat16 bf16;
typedef __attribute__((ext_vector_type(8))) short short8v;
typedef __attribute__((ext_vector_type(4))) float float4v;

#define V_    32000
#define E_    512
#define H_    512
#define T_    128
#define B_    4
#define D_    4
#define L_    2
#define C0_   2000
#define C1_   10000
#define NT_   125
#define NROW_ 2000          // B*NT*D
#define NH_   2002
#define NTOTC 2162          // 2002 + 128 + 32
#define NSLOT 252           // 17 head + 63 t0 + 172 t1 LSE partial slots per row

__device__ __forceinline__ float bf2f(bf16 v) { return __bfloat162float(v); }
__device__ __forceinline__ unsigned short f2bfu(float f) {
    bf16 h = __float2bfloat16(f);
    union { bf16 h; unsigned short u; } cv; cv.h = h; return cv.u;
}
// dtype-flag helpers: bf==1 -> bf16 input data, bf==0 -> float32
__device__ __forceinline__ float ld1(const void* p, size_t i, int bf) {
    return bf ? bf2f(((const bf16*)p)[i]) : ((const float*)p)[i];
}

__device__ __forceinline__ void lse_push(float z, float& m, float& s) {
    if (z <= m) { s += __expf(z - m); }
    else        { s = s * __expf(m - z) + 1.0f; m = z; }
}
__device__ __forceinline__ void lse_merge(float m2, float s2, float& m, float& s) {
    float mm = fmaxf(m, m2);
    s = s * __expf(m - mm) + s2 * __expf(m2 - mm);
    m = mm;
}

// ---------------- stage 0: dtype detect (G row 0 is a softmax row) --------
__global__ void k_detect(const void* __restrict__ G, int* __restrict__ flag) {
    int t = threadIdx.x;   // 64 threads
    float s32 = 0.0f;
    for (int k = t; k < 128; k += 64) s32 += ((const float*)G)[k];
    for (int off = 32; off; off >>= 1) s32 += __shfl_down(s32, off);
    if (t == 0) {
        float e32 = fabsf(s32 - 1.0f);
        *flag = (e32 < 0.05f) ? 0 : 1;   // NaN compares false -> bf16 fallback
    }
}

// ---------------- weight conversion + embedding gather (merged) -----------
// Conversion is 4-wide vectorized: every segment offset is a multiple of 4
// shorts, so a 4-group never straddles segments; bf16 source is a pure copy.
struct ConvArgs {
    const void* src[9];
    unsigned int off[10];
};
__global__ void k_wembed(ConvArgs a, unsigned short* __restrict__ wb,
                         const int* __restrict__ flagp,
                         const int* __restrict__ x, const void* __restrict__ emb,
                         float* __restrict__ embedded, float* __restrict__ f0,
                         unsigned short* __restrict__ f0b) {
    const int bf = *flagp;
    if (blockIdx.x < 1024) {
        // embedding gather: 262144 elements
        int i = blockIdx.x * 256 + threadIdx.x;
        int bt = i >> 9, e = i & 511;
        int tok = x[bt];
        float v = ld1(emb, (size_t)tok * E_ + e, bf);
        embedded[i] = v; f0[i] = v; f0b[i] = f2bfu(v);
    } else {
        unsigned int totalg = a.off[9] >> 2;          // groups of 4 shorts
        unsigned int stride = (gridDim.x - 1024) * 256;
        for (unsigned int g = (blockIdx.x - 1024) * 256 + threadIdx.x; g < totalg;
             g += stride) {
            unsigned int i = g << 2;
            int seg = 0;
            while (i >= a.off[seg + 1]) seg++;
            unsigned int o = i - a.off[seg];
            unsigned short r[4];
            if (bf) {
                *(uint2*)r = *(const uint2*)((const unsigned short*)a.src[seg] + o);
            } else {
                float4 v = *(const float4*)((const float*)a.src[seg] + o);
                r[0] = f2bfu(v.x); r[1] = f2bfu(v.y);
                r[2] = f2bfu(v.z); r[3] = f2bfu(v.w);
            }
            *(uint2*)(wb + i) = *(const uint2*)r;
        }
    }
}

// ---------------- wgt[b,i,e] = sum_j G[b,l,j,i] f[b,j,e] ------------------
__global__ void k_wgt(const void* __restrict__ G, const float* __restrict__ f,
                      unsigned short* __restrict__ wgtb, int l,
                      const int* __restrict__ flagp) {
    const int bf = *flagp;
    int i = blockIdx.x * 256 + threadIdx.x;          // 262144
    int e = i & 511;
    int bi = i >> 9;
    int b = bi >> 7, ip = bi & 127;
    size_t gbase = ((size_t)(b * L_ + l) * T_ * T_) + ip;
    const float* fb = f + (size_t)b * T_ * E_ + e;
    float acc = 0.0f;
    #pragma unroll 4
    for (int j = 0; j < T_; ++j)
        acc = fmaf(ld1(G, gbase + (size_t)j * T_, bf), fb[(size_t)j * E_], acc);
    wgtb[i] = f2bfu(acc);
}

// ---------------- MFMA bf16 GEMM core: Z[M,N] = A[M,K] * W[N,K]^T ---------
// MODE 0: gates   (store Z+bias into Zg at col zsel*zcol1; blockIdx.z picks A/W/bias)
// MODE 1: head single-pass (raw z -> out-in-place for cols<C0; LSE cols<2002 -> lsep;
//         stats 2000/2001; proj -> p0b/p1b)
// MODE 2: tail single-pass (raw z -> out-in-place at outColOff; LSE over all N)
// Raw-logit staging format: fp16 when final out dtype is bf16 (2B slots),
// fp32 when final out dtype is fp32 (4B slots) — d_out is exactly the right
// size in both modes, so no extra workspace and no flag-clobber hazard.
// lsep is slot-major [slot][row] so k_corr2 reads coalesce.
struct GemmP {
    const unsigned short* A0;
    const unsigned short* A1;
    const unsigned short* W;
    unsigned long long w1off;
    int M, N, K, Nlse;
    float* Zg; int ldz; int zcol1;
    const void* bias0; const void* bias1; int boff;
    void* zraw; int outColOff;
    float* stats;
    unsigned short* p0b;
    unsigned short* p1b;
    float* lsep; int slotBase;
    const int* lengths;
    const int* flagp;
    int gx;       // x-tile count of this segment (merged tail dispatch)
};

__device__ __forceinline__ void zstore(void* zraw, size_t i, int bf, float v) {
    if (bf) ((__half*)zraw)[i] = __float2half(v);
    else    ((float*)zraw)[i]  = v;
}

template<int MODE>
__device__ __forceinline__ void gemm_core(const GemmP& p, int bx, int by,
        unsigned short* As, unsigned short* Bs,
        float (*pm)[2], float (*ps)[2]) {
    const int bf = *p.flagp;
    const int zsel = (MODE == 0) ? blockIdx.z : 0;
    const unsigned short* A  = zsel ? p.A1 : p.A0;
    const unsigned short* Bw = p.W + (zsel ? p.w1off : 0ull);
    const int M = p.M, N = p.N, K = p.K;
    const int m0 = by * 128, n0 = bx * 128;
    const int t = threadIdx.x;
    const int wave = t >> 6, lane = t & 63;
    const int wm = wave >> 1, wn = wave & 1;
    const int quad = lane >> 4, l16 = lane & 15;

    float4v acc[4][4];
    #pragma unroll
    for (int mi = 0; mi < 4; ++mi)
        #pragma unroll
        for (int ni = 0; ni < 4; ++ni)
            acc[mi][ni] = (float4v){0.f, 0.f, 0.f, 0.f};

    for (int k0 = 0; k0 < K; k0 += 32) {
        if (k0) __syncthreads();
        #pragma unroll
        for (int i = 0; i < 2; ++i) {
            int idx = t + i * 256;
            int row = idx >> 2, seg = idx & 3;
            uint4 av = {0u, 0u, 0u, 0u};
            int gm = m0 + row;
            if (gm < M) av = *(const uint4*)(A + (size_t)gm * K + k0 + seg * 8);
            *(uint4*)(&As[row * 40 + seg * 8]) = av;
            uint4 bv = {0u, 0u, 0u, 0u};
            int gn = n0 + row;
            if (gn < N) bv = *(const uint4*)(Bw + (size_t)gn * K + k0 + seg * 8);
            *(uint4*)(&Bs[row * 40 + seg * 8]) = bv;
        }
        __syncthreads();
        short8v af[4], bfv[4];
        #pragma unroll
        for (int mi = 0; mi < 4; ++mi)
            af[mi] = *(const short8v*)(As + (wm * 64 + mi * 16 + l16) * 40 + quad * 8);
        #pragma unroll
        for (int ni = 0; ni < 4; ++ni)
            bfv[ni] = *(const short8v*)(Bs + (wn * 64 + ni * 16 + l16) * 40 + quad * 8);
        #pragma unroll
        for (int mi = 0; mi < 4; ++mi)
            #pragma unroll
            for (int ni = 0; ni < 4; ++ni)
                acc[mi][ni] = __builtin_amdgcn_mfma_f32_16x16x32_bf16(
                    af[mi], bfv[ni], acc[mi][ni], 0, 0, 0);
    }

    // ---- epilogue ----
    if (MODE == 0) {
        const void* bias = zsel ? p.bias1 : p.bias0;
        const int zcol = zsel ? p.zcol1 : 0;
        #pragma unroll
        for (int mi = 0; mi < 4; ++mi)
            #pragma unroll
            for (int r = 0; r < 4; ++r) {
                int grow = m0 + wm * 64 + mi * 16 + quad * 4 + r;
                if (grow >= M) continue;
                #pragma unroll
                for (int ni = 0; ni < 4; ++ni) {
                    int gcol = n0 + wn * 64 + ni * 16 + l16;
                    if (gcol < N)
                        p.Zg[(size_t)grow * p.ldz + zcol + gcol] =
                            acc[mi][ni][r] + ld1(bias, p.boff + gcol, bf);
                }
            }
    } else if (MODE == 1) {
        #pragma unroll
        for (int mi = 0; mi < 4; ++mi)
            #pragma unroll
            for (int r = 0; r < 4; ++r) {
                int grow = m0 + wm * 64 + mi * 16 + quad * 4 + r;
                if (grow >= M) continue;
                #pragma unroll
                for (int ni = 0; ni < 4; ++ni) {
                    int gcol = n0 + wn * 64 + ni * 16 + l16;
                    float v = acc[mi][ni][r];
                    if (gcol < C0_) zstore(p.zraw, (size_t)grow * V_ + gcol, bf, v);
                    else if (gcol < NH_) p.stats[grow * 8 + 2 + (gcol - C0_)] = v;
                    else if (gcol < 2130) p.p0b[grow * 128 + (gcol - NH_)] = f2bfu(v);
                    else if (gcol < NTOTC) p.p1b[grow * 32 + (gcol - 2130)] = f2bfu(v);
                }
            }
    } else {
        #pragma unroll
        for (int mi = 0; mi < 4; ++mi)
            #pragma unroll
            for (int r = 0; r < 4; ++r) {
                int grow = m0 + wm * 64 + mi * 16 + quad * 4 + r;
                if (grow >= M) continue;
                #pragma unroll
                for (int ni = 0; ni < 4; ++ni) {
                    int gcol = n0 + wn * 64 + ni * 16 + l16;
                    if (gcol < N)
                        zstore(p.zraw, (size_t)grow * V_ + p.outColOff + gcol, bf,
                               acc[mi][ni][r]);
                }
            }
    }

    // ---- fused per-tile LSE partials (single-pass modes) ----
    if (MODE == 1 || MODE == 2) {
        const int Nlse = p.Nlse;
        #pragma unroll
        for (int mi = 0; mi < 4; ++mi) {
            #pragma unroll
            for (int r = 0; r < 4; ++r) {
                float m = -1e30f, s = 0.0f;
                #pragma unroll
                for (int ni = 0; ni < 4; ++ni) {
                    int gcol = n0 + wn * 64 + ni * 16 + l16;
                    if (gcol < Nlse) lse_push(acc[mi][ni][r], m, s);
                }
                #pragma unroll
                for (int off = 1; off < 16; off <<= 1) {
                    float m2 = __shfl_xor(m, off), s2 = __shfl_xor(s, off);
                    lse_merge(m2, s2, m, s);
                }
                if (l16 == 0) {
                    int rl = wm * 64 + mi * 16 + quad * 4 + r;
                    pm[rl][wn] = m; ps[rl][wn] = s;
                }
            }
        }
        __syncthreads();
        if (t < 128) {
            int grow = m0 + t;
            if (grow < M) {
                float m = pm[t][0], s = ps[t][0];
                lse_merge(pm[t][1], ps[t][1], m, s);
                // slot-major layout: [slot][row]
                float* dst = p.lsep + ((size_t)(p.slotBase + bx) * NROW_ + grow) * 2;
                dst[0] = m; dst[1] = s;
            }
        }
    }
}

// __launch_bounds__(256, 2): 4 waves/block, min 2 waves/EU -> VGPR cap 256.
// Insurance against the r1 allocator heuristic that targeted 8 waves/EU
// (VGPR=64) and spilled the 64-VGPR accumulator tile to scratch.
template<int MODE>
__global__ __launch_bounds__(256, 2) void k_gemm(GemmP p) {
    __shared__ __align__(16) unsigned short As[128 * 40];
    __shared__ __align__(16) unsigned short Bs[128 * 40];
    __shared__ float pm[128][2], ps[128][2];
    gemm_core<MODE>(p, blockIdx.x, blockIdx.y, As, Bs, pm, ps);
}

// merged t0+t1 pass-A tail (both depend only on the head pass; independent
// of each other, so co-dispatch is race-free and fills the t0 tail).
__global__ __launch_bounds__(256, 2) void k_gemmT(GemmP pa, GemmP pb) {
    __shared__ __align__(16) unsigned short As[128 * 40];
    __shared__ __align__(16) unsigned short Bs[128 * 40];
    __shared__ float pm[128][2], ps[128][2];
    int bx = blockIdx.x;
    if (bx < pa.gx) gemm_core<2>(pa, bx, blockIdx.y, As, Bs, pm, ps);
    else            gemm_core<2>(pb, bx - pa.gx, blockIdx.y, As, Bs, pm, ps);
}

// ---------------- GRU pointwise ----------------
__device__ __forceinline__ float gru2(float i_r, float i_z, float i_n,
                                      float h_r, float h_z, float h_n, float h) {
    float r = 1.0f / (1.0f + __expf(-(i_r + h_r)));
    float z = 1.0f / (1.0f + __expf(-(i_z + h_z)));
    float n = tanhf(i_n + r * h_n);
    return (1.0f - z) * n + z * h;
}

__global__ void k_apply_enc(const float* __restrict__ gates,
                            const float* __restrict__ hprev,
                            float* __restrict__ hnext,
                            unsigned short* __restrict__ hnextb) {
    int i = blockIdx.x * 256 + threadIdx.x;          // 262144
    int row = i >> 9, k = i & 511;
    const float* g = gates + (size_t)row * 3072;
    float v = gru2(g[k], g[512 + k], g[1024 + k],
                   g[1536 + k], g[2048 + k], g[2560 + k], hprev[i]);
    hnext[i] = v; hnextb[i] = f2bfu(v);
}

// layer-1 apply fused with decoder prep: h0 init straight from the value in
// registers (blocks <1024) + window gather (blocks 1024..5023).
__global__ void k_apply_enc2(const float* __restrict__ gates,
                             const float* __restrict__ hprev,
                             float* __restrict__ hnext,
                             unsigned short* __restrict__ hnextb,
                             const float* __restrict__ embedded,
                             const int* __restrict__ lengths,
                             unsigned short* __restrict__ winb,
                             float* __restrict__ hdec,
                             unsigned short* __restrict__ hdecb) {
    int blk = blockIdx.x;
    if (blk < 1024) {
        int i = blk * 256 + threadIdx.x;             // 262144
        int row = i >> 9, k = i & 511;
        const float* g = gates + (size_t)row * 3072;
        float v = gru2(g[k], g[512 + k], g[1024 + k],
                       g[1536 + k], g[2048 + k], g[2560 + k], hprev[i]);
        hnext[i] = v; hnextb[i] = f2bfu(v);
        int b = row >> 7, t = row & 127;
        if (t < NT_) {
            int j = ((b * NT_ + t) << 9) + k;
            hdec[j] = v; hdecb[j] = f2bfu(v);
        }
    } else {
        int i = (blk - 1024) * 256 + threadIdx.x;    // 1,024,000
        int e = i & 511;
        int wr = i >> 9;
        int d = wr / 500, row = wr - d * 500;
        int b = row / NT_, t = row - b * NT_;
        int tok = (d == 0 && t == 0) ? (lengths[b] - 1) : (t + d - 1);
        winb[i] = f2bfu(embedded[((size_t)(b * T_ + tok) << 9) + e]);
    }
}

__global__ void k_apply_dec(const float* __restrict__ gih,
                            const float* __restrict__ ghh,
                            float* __restrict__ hdec,
                            unsigned short* __restrict__ hdecb,
                            unsigned short* __restrict__ hsb,
                            const int* __restrict__ lengths, int d) {
    int i = blockIdx.x * 256 + threadIdx.x;          // 256000
    int row = i >> 9, k = i & 511;
    int b = row / NT_, t = row - b * NT_;
    const float* gi = gih + (size_t)(d * 500 + row) * 1536;
    const float* gh = ghh + (size_t)row * 1536;
    float hn = gru2(gi[k], gi[512 + k], gi[1024 + k],
                    gh[k], gh[512 + k], gh[1024 + k], hdec[i]);
    hdec[i] = hn; hdecb[i] = f2bfu(hn);
    bool valid = (t + d) < lengths[b];
    hsb[(((size_t)row * D_ + d) << 9) + k] = valid ? f2bfu(hn) : (unsigned short)0;
}

// ---------------- combine LSE partials -> per-row corrections -------------
// lsep is slot-major: slot i, row r at lsep[(i*NROW_+r)*2] -> coalesced reads.
__global__ void k_corr2(const float* __restrict__ lsep, const float* __restrict__ stats,
                        float* __restrict__ corr) {
    int r = blockIdx.x * 256 + threadIdx.x;
    if (r >= NROW_) return;
    float m = -1e30f, s = 0.0f;
    for (int i = 0; i < 17; ++i) {
        const float* P = lsep + ((size_t)i * NROW_ + r) * 2;
        lse_merge(P[0], P[1], m, s);
    }
    float ch = m + logf(s);
    float lp0 = stats[r * 8 + 2] - ch;
    float lp1 = stats[r * 8 + 3] - ch;
    m = -1e30f; s = 0.0f;
    for (int i = 17; i < 80; ++i) {
        const float* P = lsep + ((size_t)i * NROW_ + r) * 2;
        lse_merge(P[0], P[1], m, s);
    }
    float ct0 = m + logf(s);
    m = -1e30f; s = 0.0f;
    for (int i = 80; i < 252; ++i) {
        const float* P = lsep + ((size_t)i * NROW_ + r) * 2;
        lse_merge(P[0], P[1], m, s);
    }
    float ct1 = m + logf(s);
    corr[r * 4 + 0] = ch;
    corr[r * 4 + 1] = ct0 - lp0;
    corr[r * 4 + 2] = ct1 - lp1;
}

// ------ in-place fixup: out[i] = valid ? zraw[i] - corr[seg] : 0 ----------
// Raw logits were staged into d_out itself (fp16 slots when out is bf16,
// fp32 slots when out is fp32). Each thread owns a disjoint 16/32-byte
// group (8 cols); segment boundaries 2000/10000 are multiples of 8 so a
// group never straddles segments. Per-thread read-then-write, no hazards.
__global__ void k_fix(const float* __restrict__ corr,
                      const int* __restrict__ lengths, void* __restrict__ out,
                      const int* __restrict__ flagp) {
    const int bf = *flagp;
    int idx = blockIdx.x * 256 + threadIdx.x;        // 8,000,000 groups
    if (idx >= NROW_ * (V_ / 8)) return;
    int row = idx / (V_ / 8);
    int col = (idx - row * (V_ / 8)) * 8;
    int b = row / 500;
    int tt = (row - b * 500) >> 2;
    bool valid = tt < lengths[b];
    int cri = (col < C0_) ? 0 : (col < C1_ ? 1 : 2);
    float cr = corr[row * 4 + cri];
    size_t base = (size_t)row * V_ + col;
    if (bf) {
        unsigned short* p16 = (unsigned short*)out + base;
        union { uint4 u; __half h[8]; } in;
        in.u = *(const uint4*)p16;
        union { uint4 u; unsigned short s[8]; } o;
        #pragma unroll
        for (int j = 0; j < 8; ++j)
            o.s[j] = f2bfu(valid ? (__half2float(in.h[j]) - cr) : 0.0f);
        *(uint4*)p16 = o.u;
    } else {
        float* op = (float*)out + base;
        float4 a = *(float4*)op, c = *(float4*)(op + 4);
        float4 ra = valid ? (float4){a.x - cr, a.y - cr, a.z - cr, a.w - cr}
                          : (float4){0.f, 0.f, 0.f, 0.f};
        float4 rc = valid ? (float4){c.x - cr, c.y - cr, c.z - cr, c.w - cr}
                          : (float4){0.f, 0.f, 0.f, 0.f};
        *(float4*)op = ra; *(float4*)(op + 4) = rc;
    }
}

// ---------------- workspace layout (float offsets, 16B aligned) -----------
#define OFF_EMB    0u          // 262144
#define OFF_FA     262144u     // 262144
#define OFF_FB     524288u     // 262144
#define OFF_FAB    786432u     // 131072 (262144 bf16)
#define OFF_FBB    917504u     // 131072
#define OFF_WGTB   1048576u    // 131072
#define OFF_GATES  1179648u    // 512*3072 = 1572864
#define OFF_GIH    2752512u    // 2000*1536 = 3072000
#define OFF_GHH    5824512u    // 500*1536 = 768000
#define OFF_HDEC   6592512u    // 256000
#define OFF_HDECB  6848512u    // 128000
#define OFF_WINB   6976512u    // 512000 (1,024,000 bf16)
#define OFF_HSB    7488512u    // 512000 (1,024,000 bf16)
#define OFF_P0B    8000512u    // 128000 (256000 bf16)
#define OFF_P1B    8128512u    // 32000  (64000 bf16)
#define OFF_STATS  8160512u    // 16000
#define OFF_CORR   8176512u    // 8000
#define OFF_LSEP   8184512u    // 1008000 (slot-major 252 x 2000 x 2)
#define OFF_WB     9192512u    // 3776752 (7553504 bf16)
#define OFF_FLAG   12969264u

// bf16 weight region sub-offsets (shorts)
#define WO_ENCIH   0u
#define WO_ENCHH   1572864u
#define WO_DECIH   3145728u
#define WO_DECHH   3932160u
#define WO_W1      4718592u    // head_w rows, t0_proj, t1_proj (2162x512)
#define WO_T0O     5825536u    // 8000x128
#define WO_T1O     6849536u    // 22000x32
#define WO_END     7553504u

static inline GemmP mkp(const unsigned short* A0, const unsigned short* A1,
                        const unsigned short* W, unsigned long long w1off,
                        int M, int N, int K, int Nlse,
                        float* Zg, int ldz, int zcol1,
                        const void* bias0, const void* bias1, int boff,
                        void* zraw, int outColOff, float* stats,
                        unsigned short* p0b, unsigned short* p1b,
                        float* lsep, int slotBase,
                        const int* lengths, const int* flagp) {
    GemmP p;
    p.A0 = A0; p.A1 = A1; p.W = W; p.w1off = w1off;
    p.M = M; p.N = N; p.K = K; p.Nlse = Nlse;
    p.Zg = Zg; p.ldz = ldz; p.zcol1 = zcol1;
    p.bias0 = bias0; p.bias1 = bias1; p.boff = boff;
    p.zraw = zraw; p.outColOff = outColOff; p.stats = stats;
    p.p0b = p0b; p.p1b = p1b; p.lsep = lsep; p.slotBase = slotBase;
    p.lengths = lengths; p.flagp = flagp; p.gx = 0;
    return p;
}

extern "C" void kernel_launch(void* const* d_in, const int* in_sizes, int n_in,
                              void* d_out, int out_size, void* d_ws, size_t ws_size,
                              hipStream_t stream) {
    (void)in_sizes; (void)n_in; (void)out_size; (void)ws_size;
    const int*  x        = (const int*)d_in[0];
    const int*  lengths  = (const int*)d_in[1];
    const void* G        = d_in[2];
    const void* emb      = d_in[3];
    const void* enc_w_ih = d_in[4];
    const void* enc_w_hh = d_in[5];
    const void* enc_b_ih = d_in[6];
    const void* enc_b_hh = d_in[7];
    const void* dec_w_ih = d_in[8];
    const void* dec_w_hh = d_in[9];
    const void* dec_b_ih = d_in[10];
    const void* dec_b_hh = d_in[11];
    const void* head_w   = d_in[12];
    const void* t0_proj  = d_in[13];
    const void* t0_out   = d_in[14];
    const void* t1_proj  = d_in[15];
    const void* t1_out   = d_in[16];

    float* ws = (float*)d_ws;
    float* embedded = ws + OFF_EMB;
    float* fA    = ws + OFF_FA;
    float* fB    = ws + OFF_FB;
    unsigned short* fAb  = (unsigned short*)(ws + OFF_FAB);
    unsigned short* fBb  = (unsigned short*)(ws + OFF_FBB);
    unsigned short* wgtb = (unsigned short*)(ws + OFF_WGTB);
    float* gates = ws + OFF_GATES;
    float* gih   = ws + OFF_GIH;
    float* ghh   = ws + OFF_GHH;
    float* hdec  = ws + OFF_HDEC;
    unsigned short* hdecb = (unsigned short*)(ws + OFF_HDECB);
    unsigned short* winb  = (unsigned short*)(ws + OFF_WINB);
    unsigned short* hsb   = (unsigned short*)(ws + OFF_HSB);
    unsigned short* p0b   = (unsigned short*)(ws + OFF_P0B);
    unsigned short* p1b   = (unsigned short*)(ws + OFF_P1B);
    float* stats = ws + OFF_STATS;
    float* corr  = ws + OFF_CORR;
    float* lsep  = ws + OFF_LSEP;
    unsigned short* WB = (unsigned short*)(ws + OFF_WB);
    int* flagp = (int*)(ws + OFF_FLAG);
    void* out = d_out;

    k_detect<<<1, 64, 0, stream>>>(G, flagp);

    ConvArgs ca;
    ca.src[0] = enc_w_ih; ca.src[1] = enc_w_hh; ca.src[2] = dec_w_ih;
    ca.src[3] = dec_w_hh; ca.src[4] = head_w;   ca.src[5] = t0_proj;
    ca.src[6] = t1_proj;  ca.src[7] = t0_out;   ca.src[8] = t1_out;
    ca.off[0] = WO_ENCIH; ca.off[1] = WO_ENCHH; ca.off[2] = WO_DECIH;
    ca.off[3] = WO_DECHH; ca.off[4] = WO_W1;
    ca.off[5] = WO_W1 + 2002u * 512u;
    ca.off[6] = WO_W1 + 2130u * 512u;
    ca.off[7] = WO_T0O;   ca.off[8] = WO_T1O;   ca.off[9] = WO_END;
    k_wembed<<<3072, 256, 0, stream>>>(ca, WB, flagp, x, emb, embedded, fA, fAb);

    // encoder layer 0: fA -> fB  (ih + hh fused via gridDim.z)
    k_wgt<<<1024, 256, 0, stream>>>(G, fA, wgtb, 0, flagp);
    k_gemm<0><<<dim3(12, 4, 2), 256, 0, stream>>>(mkp(
        wgtb, fAb, WB + WO_ENCIH, (unsigned long long)(WO_ENCHH - WO_ENCIH),
        512, 1536, 512, 0, gates, 3072, 1536, enc_b_ih, enc_b_hh, 0,
        nullptr, 0, nullptr, nullptr, nullptr, nullptr, 0, lengths, flagp));
    k_apply_enc<<<1024, 256, 0, stream>>>(gates, fA, fB, fBb);

    // encoder layer 1: fB -> fA, fused with decoder prep (h0 + window gather)
    k_wgt<<<1024, 256, 0, stream>>>(G, fB, wgtb, 1, flagp);
    k_gemm<0><<<dim3(12, 4, 2), 256, 0, stream>>>(mkp(
        wgtb, fBb, WB + WO_ENCIH + 786432u, (unsigned long long)(WO_ENCHH - WO_ENCIH),
        512, 1536, 512, 0, gates, 3072, 1536, enc_b_ih, enc_b_hh, 1536,
        nullptr, 0, nullptr, nullptr, nullptr, nullptr, 0, lengths, flagp));
    k_apply_enc2<<<5024, 256, 0, stream>>>(gates, fB, fA, fAb, embedded, lengths,
                                           winb, hdec, hdecb);

    // batched decoder ih GEMM (all 4 d-steps at once)
    k_gemm<0><<<dim3(12, 16, 1), 256, 0, stream>>>(mkp(
        winb, nullptr, WB + WO_DECIH, 0ull, 2000, 1536, 512, 0,
        gih, 1536, 0, dec_b_ih, nullptr, 0,
        nullptr, 0, nullptr, nullptr, nullptr, nullptr, 0, lengths, flagp));

    // serial decoder hh steps
    for (int d = 0; d < D_; ++d) {
        k_gemm<0><<<dim3(12, 4, 1), 256, 0, stream>>>(mkp(
            hdecb, nullptr, WB + WO_DECHH, 0ull, 500, 1536, 512, 0,
            ghh, 1536, 0, dec_b_hh, nullptr, 0,
            nullptr, 0, nullptr, nullptr, nullptr, nullptr, 0, lengths, flagp));
        k_apply_dec<<<1000, 256, 0, stream>>>(gih, ghh, hdec, hdecb, hsb, lengths, d);
    }

    // adaptive softmax — single pass: raw logits (into out) + LSE partials
    k_gemm<1><<<dim3(17, 16, 1), 256, 0, stream>>>(mkp(
        hsb, nullptr, WB + WO_W1, 0ull, NROW_, NTOTC, 512, NH_,
        nullptr, 0, 0, nullptr, nullptr, 0, out, 0,
        stats, p0b, p1b, lsep, 0, lengths, flagp));
    // t0 + t1 tails merged into one dispatch (independent of each other)
    {
        GemmP pa = mkp(p0b, nullptr, WB + WO_T0O, 0ull, NROW_, 8000, 128, 8000,
                       nullptr, 0, 0, nullptr, nullptr, 0, out, C0_,
                       stats, nullptr, nullptr, lsep, 17, lengths, flagp);
        pa.gx = 63;
        GemmP pb = mkp(p1b, nullptr, WB + WO_T1O, 0ull, NROW_, 22000, 32, 22000,
                       nullptr, 0, 0, nullptr, nullptr, 0, out, C1_,
                       stats, nullptr, nullptr, lsep, 80, lengths, flagp);
        pb.gx = 172;
        k_gemmT<<<dim3(235, 16, 1), 256, 0, stream>>>(pa, pb);
    }

    k_corr2<<<8, 256, 0, stream>>>(lsep, stats, corr);

    // in-place fixup: out = valid ? z - corr : 0  (replaces pass-B GEMMs)
    k_fix<<<31250, 256, 0, stream>>>(corr, lengths, out, flagp);
}